// Round 1
// baseline (20734.520 us; speedup 1.0000x reference)
//
#include <hip/hip_runtime.h>
#include <cstdint>
#include <cstddef>

#define SEQ   512
#define BATCH 64
#define INDIM 512
#define HID   1024

typedef short bf16x8 __attribute__((ext_vector_type(8)));
typedef float f32x4  __attribute__((ext_vector_type(4)));
typedef unsigned long long ull;

#define MFMA16(A,B,C) __builtin_amdgcn_mfma_f32_16x16x32_bf16(A,B,C,0,0,0)

// ---- workspace layout (bytes) ----
// ht : [4 grp][2 buf][32 kc][64 lane][8 e] u64  (tag<<32 | hi<<16 | lo)  1,048,576 B
// rt : [4 grp][32 kc][64 lane][8 e] u64                                    524,288 B
// W_hi : [64 jb][48 kc][3 gate][64 lane][8] bf16                         9,437,184 B
// W_lo : same                                                            9,437,184 B
#define WS_HT  0
#define WS_RT  1048576
#define WS_WHI 1572864
#define WS_WLO (WS_WHI + 9437184)
#define WS_END (WS_WLO + 9437184)   // 20,447,232 B (ws proven >= 43 MB earlier)

__device__ __forceinline__ unsigned short f2bf(float f) {
  unsigned u = __float_as_uint(f);
  unsigned r = (u + 0x7fffu + ((u >> 16) & 1u)) >> 16;  // RNE
  return (unsigned short)r;
}
__device__ __forceinline__ float bf2f(unsigned short h) {
  return __uint_as_float(((unsigned)h) << 16);
}
__device__ __forceinline__ void splitf(float x, unsigned short& hi, unsigned short& lo) {
  unsigned short h = f2bf(x);
  float r = x - bf2f(h);          // exact
  hi = h; lo = f2bf(r);           // combined rel err ~2^-18
}

// ---------------- prep: pack weights (B-fragment order, hi+lo) ----------------
__global__ void prep_w(const float* __restrict__ Wz, const float* __restrict__ Wr,
                       const float* __restrict__ Wm,
                       bf16x8* __restrict__ wh, bf16x8* __restrict__ wl) {
  int n    = blockIdx.x * 256 + threadIdx.x;     // 589,824 threads
  int lane = n & 63;
  int m    = n >> 6;
  int g    = m % 3;
  int m2   = m / 3;
  int kc   = m2 % 48;
  int jb   = m2 / 48;
  const float* W = (g == 0) ? Wz : (g == 1) ? Wr : Wm;
  int k0 = kc*32 + ((lane >> 4) << 3);
  int nn = jb*16 + (lane & 15);
  bf16x8 vh, vl;
  #pragma unroll
  for (int j = 0; j < 8; ++j) {
    unsigned short a, b;
    splitf(W[(size_t)(k0 + j)*HID + nn], a, b);
    vh[j] = (short)a; vl[j] = (short)b;
  }
  wh[n] = vh; wl[n] = vl;
}

// ---------------- prep: pack init_h (tagged u64, tag=1) into buf 0 ----------------
__global__ void prep_h(const float* __restrict__ h0, ull* __restrict__ ht) {
  int n = blockIdx.x * 256 + threadIdx.x;        // 8192 threads
  int b = n >> 7;
  int j = (n & 127) << 3;
  const float* s = h0 + (size_t)b*HID + j;
  float4 f0 = ((const float4*)s)[0];
  float4 f1 = ((const float4*)s)[1];
  float v[8] = {f0.x,f0.y,f0.z,f0.w,f1.x,f1.y,f1.z,f1.w};
  int g    = b >> 4;
  int kc2  = j >> 5;
  int lane = (b & 15) + (((j >> 3) & 3) << 4);
  size_t base = ((size_t)(g*2 + 0)*32 + kc2)*512 + (size_t)lane*8;  // buf 0
  #pragma unroll
  for (int q = 0; q < 8; ++q) {
    unsigned short a, c;
    splitf(v[q], a, c);
    ht[base + q] = ((ull)1u << 32) | (ull)(((unsigned)a << 16) | (unsigned)c);
  }
}

// gather 8 tagged A-fragments (hi+lo) for one wave's K-slice.
// base points at [kc=w*8][lane][e=0]; kc stride = 512 u64.
// stage 1: spin on one sentinel word per frag (covers all 16 producer blocks,
//          8 B/lane/iter -> negligible LLC pressure).
// stage 2: full 64-word gather + tag verify (normally a single pass).
__device__ __forceinline__ void gather_tagged(bf16x8* Fh, bf16x8* Fl,
                                              const ull* __restrict__ base,
                                              unsigned tgt) {
  for (;;) {
    bool ok = true;
    #pragma unroll
    for (int i = 0; i < 8; ++i) {
      ull s = __hip_atomic_load(base + (size_t)i*512,
                                __ATOMIC_RELAXED, __HIP_MEMORY_SCOPE_AGENT);
      ok &= ((unsigned)(s >> 32) == tgt);
    }
    if (__ballot(ok) == ~0ull) break;
    __builtin_amdgcn_s_sleep(1);
  }
  for (;;) {
    ull v[8][8];
    #pragma unroll
    for (int i = 0; i < 8; ++i) {
      #pragma unroll
      for (int e = 0; e < 8; ++e)
        v[i][e] = __hip_atomic_load(base + (size_t)i*512 + e,
                                    __ATOMIC_RELAXED, __HIP_MEMORY_SCOPE_AGENT);
    }
    bool ok = true;
    #pragma unroll
    for (int i = 0; i < 8; ++i) {
      #pragma unroll
      for (int e = 0; e < 8; ++e)
        ok &= ((unsigned)(v[i][e] >> 32) == tgt);
    }
    if (__ballot(ok) == ~0ull) {
      #pragma unroll
      for (int i = 0; i < 8; ++i) {
        bf16x8 h8, l8;
        #pragma unroll
        for (int e = 0; e < 8; ++e) {
          unsigned p = (unsigned)v[i][e];
          h8[e] = (short)(p >> 16);
          l8[e] = (short)(p & 0xffffu);
        }
        Fh[i] = h8; Fl[i] = l8;
      }
      return;
    }
    __builtin_amdgcn_s_sleep(1);
  }
}

// ---------------- main persistent GRU kernel ----------------
// 256 blocks x 256 threads. blockIdx = g*64 + jb.
// Block (g,jb): batch rows [g*16,g*16+16), HID cols [jb*16,jb*16+16), full K.
// 4 waves K-split (8 kc each of the h-part); partials reduced via LDS.
// Cross-block exchange: self-validating tagged u64 words (no flags, no fences).
__global__ __launch_bounds__(256, 1)
void gru_main(const float* __restrict__ emb,
              const float* __restrict__ bz, const float* __restrict__ br,
              const float* __restrict__ bm, const float* __restrict__ init_h,
              float* __restrict__ out,
              const bf16x8* __restrict__ wh_all, const bf16x8* __restrict__ wl_all,
              ull* __restrict__ ht, ull* __restrict__ rt)
{
  const int tid  = threadIdx.x;
  const int w    = tid >> 6;
  const int lane = tid & 63;
  const int jb   = blockIdx.x & 63;
  const int g    = blockIdx.x >> 6;
  const int jc   = jb*16 + (lane & 15);   // C/D col
  const int rb   = (lane >> 4) << 2;      // C/D row base within 16-row tile
  const int bb   = g*16 + rb;             // global batch row base

  const float bzj = bz[jc], brj = br[jc], bmj = bm[jc];
  float st[4];
  #pragma unroll
  for (int r = 0; r < 4; ++r) st[r] = init_h[(size_t)(bb + r)*HID + jc];

  __shared__ f32x4 red1[3][4][64];   // az, ar, amx partials
  __shared__ f32x4 red2[4][64];      // amh partials

  // ---- preload this wave's h-part W slice into registers (48 frags) ----
  const bf16x8* whB = wh_all + ((size_t)jb*48*3)*64 + lane;
  const bf16x8* wlB = wl_all + ((size_t)jb*48*3)*64 + lane;
  bf16x8 Wh[8][3], Wl[8][3];
  #pragma unroll
  for (int i = 0; i < 8; ++i) {
    int kc = 16 + w*8 + i;
    #pragma unroll
    for (int gt = 0; gt < 3; ++gt) {
      Wh[i][gt] = whB[(size_t)(kc*3 + gt)*64];
      Wl[i][gt] = wlB[(size_t)(kc*3 + gt)*64];
    }
  }

  // publish-index constants (owner side)
  const int kc2w   = jc >> 5;
  const int l2base = ((jc & 31) >> 3) << 4;
  const int e7     = jc & 7;

  // gather base pointers (u64 granularity)
  const ull* hb0   = ht + (size_t)(g*2 + 0)*16384 + (size_t)(w*8)*512 + (size_t)lane*8;
  const ull* hb1   = hb0 + 16384;
  const ull* rbase = rt + (size_t)g*16384 + (size_t)(w*8)*512 + (size_t)lane*8;

  // e-part A source: lane holds emb[t][g*16+(lane&15)][kce*32+(lane>>4)*8 .. +7]
  const float* ebase = emb + (size_t)(g*16 + (lane & 15))*INDIM + ((lane >> 4) << 3);

  for (int t = 0; t < SEQ; ++t) {
    f32x4 az  = {0.f,0.f,0.f,0.f};
    f32x4 ar  = {0.f,0.f,0.f,0.f};
    f32x4 amx = {0.f,0.f,0.f,0.f};
    f32x4 amh = {0.f,0.f,0.f,0.f};

    // ---- e-part (x-projections, K-slice kce = w*4..w*4+3): overlaps h wait ----
    const float* et = ebase + (size_t)t*(BATCH*INDIM);
    #pragma unroll
    for (int q = 0; q < 4; ++q) {
      int kce = w*4 + q;
      const float* s = et + kce*32;
      float4 f0 = ((const float4*)s)[0];
      float4 f1 = ((const float4*)s)[1];
      float v[8] = {f0.x,f0.y,f0.z,f0.w,f1.x,f1.y,f1.z,f1.w};
      bf16x8 eh, el;
      #pragma unroll
      for (int qq = 0; qq < 8; ++qq) {
        unsigned short a, b;
        splitf(v[qq], a, b);
        eh[qq] = (short)a; el[qq] = (short)b;
      }
      bf16x8 wzh = whB[(size_t)(kce*3+0)*64], wzl = wlB[(size_t)(kce*3+0)*64];
      bf16x8 wrh = whB[(size_t)(kce*3+1)*64], wrl = wlB[(size_t)(kce*3+1)*64];
      bf16x8 wmh = whB[(size_t)(kce*3+2)*64], wml = wlB[(size_t)(kce*3+2)*64];
      az  = MFMA16(eh, wzh, az);  az  = MFMA16(eh, wzl, az);  az  = MFMA16(el, wzh, az);
      ar  = MFMA16(eh, wrh, ar);  ar  = MFMA16(eh, wrl, ar);  ar  = MFMA16(el, wrh, ar);
      amx = MFMA16(eh, wmh, amx); amx = MFMA16(eh, wml, amx); amx = MFMA16(el, wmh, amx);
    }

    // ---- phase 1: gather h(t) (tag = t+1), z/r h-matmul over K-slice ----
    const int buf = t & 1;
    bf16x8 Ah[8], Al[8];
    gather_tagged(Ah, Al, buf ? hb1 : hb0, (unsigned)(t + 1));
    #pragma unroll
    for (int i = 0; i < 8; ++i) {
      az = MFMA16(Ah[i], Wh[i][0], az);
      az = MFMA16(Ah[i], Wl[i][0], az);
      az = MFMA16(Al[i], Wh[i][0], az);
      ar = MFMA16(Ah[i], Wh[i][1], ar);
      ar = MFMA16(Ah[i], Wl[i][1], ar);
      ar = MFMA16(Al[i], Wh[i][1], ar);
    }

    // ---- reduce az, ar (and amx, off the phase-2 critical path) ----
    red1[0][w][lane] = az;
    red1[1][w][lane] = ar;
    red1[2][w][lane] = amx;
    __syncthreads();                                   // S1
    f32x4 azF  = red1[0][0][lane] + red1[0][1][lane] + red1[0][2][lane] + red1[0][3][lane];
    f32x4 arF  = red1[1][0][lane] + red1[1][1][lane] + red1[1][2][lane] + red1[1][3][lane];
    f32x4 amxF = red1[2][0][lane] + red1[2][1][lane] + red1[2][2][lane] + red1[2][3][lane];

    // ---- pointwise 1: z, r, rh = r*h ; publish tagged rh (wave 0, fire&forget) ----
    float z[4];
    #pragma unroll
    for (int r = 0; r < 4; ++r) {
      z[r]     = 1.f / (1.f + __expf(-(azF[r] + bzj)));
      float rr = 1.f / (1.f + __expf(-(arF[r] + brj)));
      float rhv = rr * st[r];
      if (w == 0) {
        unsigned short sh, sl;
        splitf(rhv, sh, sl);
        int lane2 = (rb + r) + l2base;
        size_t eidx = ((size_t)kc2w*64 + lane2)*8 + e7;
        ull wd = ((ull)(unsigned)(t + 1) << 32)
               | (ull)(((unsigned)sh << 16) | (unsigned)sl);
        __hip_atomic_store(rt + (size_t)g*16384 + eidx, wd,
                           __ATOMIC_RELAXED, __HIP_MEMORY_SCOPE_AGENT);
      }
    }

    // ---- phase 2: gather rh(t) (tag = t+1), m h-matmul ----
    bf16x8 Bh[8], Bl[8];
    gather_tagged(Bh, Bl, rbase, (unsigned)(t + 1));
    #pragma unroll
    for (int i = 0; i < 8; ++i) {
      amh = MFMA16(Bh[i], Wh[i][2], amh);
      amh = MFMA16(Bh[i], Wl[i][2], amh);
      amh = MFMA16(Bl[i], Wh[i][2], amh);
    }

    // ---- reduce amh ----
    red2[w][lane] = amh;
    __syncthreads();                                   // S2
    f32x4 amhF = red2[0][lane] + red2[1][lane] + red2[2][lane] + red2[3][lane];

    // ---- pointwise 2: h_tilde, h_new ; publish tagged h(t+1) (wave 0) ----
    const int obuf = buf ^ 1;
    float hnv[4];
    #pragma unroll
    for (int r = 0; r < 4; ++r) {
      float pm = amxF[r] + bmj + amhF[r];
      float e2 = __expf(2.f*pm);
      float htl = 1.f - 2.f/(e2 + 1.f);
      float hn = st[r] + z[r]*(htl - st[r]);
      st[r] = hn; hnv[r] = hn;
      if (w == 0) {
        unsigned short sh, sl;
        splitf(hn, sh, sl);
        int lane2 = (rb + r) + l2base;
        size_t eidx = ((size_t)kc2w*64 + lane2)*8 + e7;
        ull wd = ((ull)(unsigned)(t + 2) << 32)
               | (ull)(((unsigned)sh << 16) | (unsigned)sl);
        __hip_atomic_store(ht + (size_t)(g*2 + obuf)*16384 + eidx, wd,
                           __ATOMIC_RELAXED, __HIP_MEMORY_SCOPE_AGENT);
      }
    }

    // ---- output (off the inter-block critical path) ----
    if (w == 0) {
      #pragma unroll
      for (int r = 0; r < 4; ++r)
        __builtin_nontemporal_store(hnv[r],
            out + (size_t)(bb + r)*(SEQ*HID) + (size_t)t*HID + jc);
    }
  }
}

extern "C" void kernel_launch(void* const* d_in, const int* in_sizes, int n_in,
                              void* d_out, int out_size, void* d_ws, size_t ws_size,
                              hipStream_t stream) {
  const float* emb = (const float*)d_in[0];
  const float* h0  = (const float*)d_in[1];
  const float* Wz  = (const float*)d_in[2];
  const float* bz  = (const float*)d_in[3];
  const float* Wr  = (const float*)d_in[4];
  const float* br  = (const float*)d_in[5];
  const float* Wm  = (const float*)d_in[6];
  const float* bm  = (const float*)d_in[7];
  float* out = (float*)d_out;

  if (ws_size < (size_t)WS_END) return;

  char* ws = (char*)d_ws;
  ull*    htp = (ull*)(ws + WS_HT);
  ull*    rtp = (ull*)(ws + WS_RT);
  bf16x8* wph = (bf16x8*)(ws + WS_WHI);
  bf16x8* wpl = (bf16x8*)(ws + WS_WLO);

  hipMemsetAsync(ws, 0, WS_WHI, stream);          // zero ht + rt (tags != any target)
  prep_w<<<2304, 256, 0, stream>>>(Wz, Wr, Wm, wph, wpl);
  prep_h<<<32,   256, 0, stream>>>(h0, htp);
  gru_main<<<256, 256, 0, stream>>>(emb, bz, br, bm, h0, out,
                                    wph, wpl, htp, rtp);
}

// Round 2
// 15395.442 us; speedup vs baseline: 1.3468x; 1.3468x over previous
//
#include <hip/hip_runtime.h>
#include <cstdint>
#include <cstddef>

#define SEQ   512
#define BATCH 64
#define INDIM 512
#define HID   1024

typedef short bf16x8 __attribute__((ext_vector_type(8)));
typedef float f32x4  __attribute__((ext_vector_type(4)));
typedef unsigned long long ull;

#define MFMA16(A,B,C) __builtin_amdgcn_mfma_f32_16x16x32_bf16(A,B,C,0,0,0)

// ---- workspace layout (bytes) ----
// ht : [4 grp][2 buf][32 kc][64 lane][8 e] u64  (tag<<32 | hi<<16 | lo)  1,048,576 B
// rt : [4 grp][32 kc][64 lane][8 e] u64                                    524,288 B
// W_hi : [64 jb][48 kc][3 gate][64 lane][8] bf16                         9,437,184 B
// W_lo : same                                                            9,437,184 B
#define WS_HT  0
#define WS_RT  1048576
#define WS_WHI 1572864
#define WS_WLO (WS_WHI + 9437184)
#define WS_END (WS_WLO + 9437184)

__device__ __forceinline__ unsigned short f2bf(float f) {
  unsigned u = __float_as_uint(f);
  unsigned r = (u + 0x7fffu + ((u >> 16) & 1u)) >> 16;  // RNE
  return (unsigned short)r;
}
__device__ __forceinline__ float bf2f(unsigned short h) {
  return __uint_as_float(((unsigned)h) << 16);
}
__device__ __forceinline__ void splitf(float x, unsigned short& hi, unsigned short& lo) {
  unsigned short h = f2bf(x);
  float r = x - bf2f(h);          // exact
  hi = h; lo = f2bf(r);           // combined rel err ~2^-18
}

// ---------------- prep: pack weights (B-fragment order, hi+lo) ----------------
__global__ void prep_w(const float* __restrict__ Wz, const float* __restrict__ Wr,
                       const float* __restrict__ Wm,
                       bf16x8* __restrict__ wh, bf16x8* __restrict__ wl) {
  int n    = blockIdx.x * 256 + threadIdx.x;     // 589,824 threads
  int lane = n & 63;
  int m    = n >> 6;
  int g    = m % 3;
  int m2   = m / 3;
  int kc   = m2 % 48;
  int jb   = m2 / 48;
  const float* W = (g == 0) ? Wz : (g == 1) ? Wr : Wm;
  int k0 = kc*32 + ((lane >> 4) << 3);
  int nn = jb*16 + (lane & 15);
  bf16x8 vh, vl;
  #pragma unroll
  for (int j = 0; j < 8; ++j) {
    unsigned short a, b;
    splitf(W[(size_t)(k0 + j)*HID + nn], a, b);
    vh[j] = (short)a; vl[j] = (short)b;
  }
  wh[n] = vh; wl[n] = vl;
}

// ---------------- prep: pack init_h (tagged u64, tag=1) into buf 0 ----------------
__global__ void prep_h(const float* __restrict__ h0, ull* __restrict__ ht) {
  int n = blockIdx.x * 256 + threadIdx.x;        // 8192 threads
  int b = n >> 7;
  int j = (n & 127) << 3;
  const float* s = h0 + (size_t)b*HID + j;
  float4 f0 = ((const float4*)s)[0];
  float4 f1 = ((const float4*)s)[1];
  float v[8] = {f0.x,f0.y,f0.z,f0.w,f1.x,f1.y,f1.z,f1.w};
  int g    = b >> 4;
  int kc2  = j >> 5;
  int lane = (b & 15) + (((j >> 3) & 3) << 4);
  size_t base = ((size_t)(g*2 + 0)*32 + kc2)*512 + (size_t)lane*8;  // buf 0
  #pragma unroll
  for (int q = 0; q < 8; ++q) {
    unsigned short a, c;
    splitf(v[q], a, c);
    ht[base + q] = ((ull)1u << 32) | (ull)(((unsigned)a << 16) | (unsigned)c);
  }
}

// ---- constant-footprint spin: 16 sentinel words (1 KB) per wave ----
// Producer (g,jb') wave0's LAST publish store lands at slot
// [kc = jb'>>1][lane2 = (jb'&1)*32 + 31][e = 7]  (written by lane 63, r=3).
// Wave w's 16 producers are jb' = 16w .. 16w+15; lane polls producer (lane&15).
__device__ __forceinline__ void spin16(const ull* __restrict__ gbase,
                                       int w, int lane, unsigned tgt) {
  int p = lane & 15;
  const ull* s = gbase + (size_t)(8*w + (p >> 1))*512
                       + (size_t)(((p & 1) << 5) | 31)*8 + 7;
  for (;;) {
    ull v = __hip_atomic_load(s, __ATOMIC_RELAXED, __HIP_MEMORY_SCOPE_AGENT);
    if (__ballot((unsigned)(v >> 32) >= tgt) == ~0ull) return;
    __builtin_amdgcn_s_sleep(1);
  }
}

// ---- full tagged gather of this wave's 8 A-fragments (hi+lo), verify tags ----
// base = wave/lane gather base; kc stride = 512 u64.
__device__ __forceinline__ bool try_gather(bf16x8* Fh, bf16x8* Fl,
                                           const ull* __restrict__ base,
                                           unsigned tgt) {
  bool ok = true;
  #pragma unroll
  for (int i = 0; i < 8; ++i) {
    ull v[8];
    #pragma unroll
    for (int e = 0; e < 8; ++e)
      v[e] = __hip_atomic_load(base + (size_t)i*512 + e,
                               __ATOMIC_RELAXED, __HIP_MEMORY_SCOPE_AGENT);
    bf16x8 h8, l8;
    #pragma unroll
    for (int e = 0; e < 8; ++e) {
      ok &= ((unsigned)(v[e] >> 32) == tgt);
      unsigned pp = (unsigned)v[e];
      h8[e] = (short)(pp >> 16);
      l8[e] = (short)(pp & 0xffffu);
    }
    Fh[i] = h8; Fl[i] = l8;
  }
  return ok;
}

// ---------------- main persistent GRU kernel ----------------
// 256 blocks x 256 threads. blockIdx = g*64 + jb.
// Block (g,jb): batch rows [g*16,g*16+16), HID cols [jb*16,jb*16+16), full K.
// 4 waves K-split (8 kc each of the h-part); partials reduced via LDS.
// Cross-block exchange: self-validating tagged u64 words, fire-and-forget
// producers (no release fences), constant-footprint sentinel spin.
__global__ __launch_bounds__(256, 1)
void gru_main(const float* __restrict__ emb,
              const float* __restrict__ bz, const float* __restrict__ br,
              const float* __restrict__ bm, const float* __restrict__ init_h,
              float* __restrict__ out,
              const bf16x8* __restrict__ wh_all, const bf16x8* __restrict__ wl_all,
              ull* __restrict__ ht, ull* __restrict__ rt)
{
  const int tid  = threadIdx.x;
  const int w    = tid >> 6;
  const int lane = tid & 63;
  const int jb   = blockIdx.x & 63;
  const int g    = blockIdx.x >> 6;
  const int jc   = jb*16 + (lane & 15);   // C/D col
  const int rb   = (lane >> 4) << 2;      // C/D row base within 16-row tile
  const int bb   = g*16 + rb;             // global batch row base

  const float bzj = bz[jc], brj = br[jc], bmj = bm[jc];
  float st[4];
  #pragma unroll
  for (int r = 0; r < 4; ++r) st[r] = init_h[(size_t)(bb + r)*HID + jc];

  __shared__ f32x4 red1[3][4][64];   // az, ar, amx partials
  __shared__ f32x4 red2[4][64];      // amh partials

  // ---- preload this wave's h-part W slice into registers (48 frags) ----
  const bf16x8* whB = wh_all + ((size_t)jb*48*3)*64 + lane;
  const bf16x8* wlB = wl_all + ((size_t)jb*48*3)*64 + lane;
  bf16x8 Wh[8][3], Wl[8][3];
  #pragma unroll
  for (int i = 0; i < 8; ++i) {
    int kc = 16 + w*8 + i;
    #pragma unroll
    for (int gt = 0; gt < 3; ++gt) {
      Wh[i][gt] = whB[(size_t)(kc*3 + gt)*64];
      Wl[i][gt] = wlB[(size_t)(kc*3 + gt)*64];
    }
  }

  // publish-index constants (owner side)
  const int kc2w   = jc >> 5;
  const int l2base = ((jc & 31) >> 3) << 4;
  const int e7     = jc & 7;

  // group-level publish-buffer bases and this wave's gather offset
  const ull* hgrp0 = ht + (size_t)(g*2 + 0)*16384;
  const ull* hgrp1 = hgrp0 + 16384;
  const ull* rgrp  = rt + (size_t)g*16384;
  const size_t woff = (size_t)(w*8)*512 + (size_t)lane*8;

  // e-part A source: lane holds emb[t][g*16+(lane&15)][kce*32+(lane>>4)*8 .. +7]
  const float* ebase = emb + (size_t)(g*16 + (lane & 15))*INDIM + ((lane >> 4) << 3);

  for (int t = 0; t < SEQ; ++t) {
    f32x4 az  = {0.f,0.f,0.f,0.f};
    f32x4 ar  = {0.f,0.f,0.f,0.f};
    f32x4 amx = {0.f,0.f,0.f,0.f};
    f32x4 amh = {0.f,0.f,0.f,0.f};

    // ---- e-part (x-projections, K-slice kce = w*4..w*4+3): overlaps h wait ----
    const float* et = ebase + (size_t)t*(BATCH*INDIM);
    #pragma unroll
    for (int q = 0; q < 4; ++q) {
      int kce = w*4 + q;
      const float* s = et + kce*32;
      float4 f0 = ((const float4*)s)[0];
      float4 f1 = ((const float4*)s)[1];
      float v[8] = {f0.x,f0.y,f0.z,f0.w,f1.x,f1.y,f1.z,f1.w};
      bf16x8 eh, el;
      #pragma unroll
      for (int qq = 0; qq < 8; ++qq) {
        unsigned short a, b;
        splitf(v[qq], a, b);
        eh[qq] = (short)a; el[qq] = (short)b;
      }
      bf16x8 wzh = whB[(size_t)(kce*3+0)*64], wzl = wlB[(size_t)(kce*3+0)*64];
      bf16x8 wrh = whB[(size_t)(kce*3+1)*64], wrl = wlB[(size_t)(kce*3+1)*64];
      bf16x8 wmh = whB[(size_t)(kce*3+2)*64], wml = wlB[(size_t)(kce*3+2)*64];
      az  = MFMA16(eh, wzh, az);  az  = MFMA16(eh, wzl, az);  az  = MFMA16(el, wzh, az);
      ar  = MFMA16(eh, wrh, ar);  ar  = MFMA16(eh, wrl, ar);  ar  = MFMA16(el, wrh, ar);
      amx = MFMA16(eh, wmh, amx); amx = MFMA16(eh, wml, amx); amx = MFMA16(el, wmh, amx);
    }

    // ---- phase 1: wait + gather h(t) (tag = t+1), z/r h-matmul over K-slice ----
    const int buf = t & 1;
    const ull* gb = buf ? hgrp1 : hgrp0;
    spin16(gb, w, lane, (unsigned)(t + 1));
    bf16x8 Ah[8], Al[8];
    while (__ballot(try_gather(Ah, Al, gb + woff, (unsigned)(t + 1))) != ~0ull)
      __builtin_amdgcn_s_sleep(1);
    #pragma unroll
    for (int i = 0; i < 8; ++i) {
      az = MFMA16(Ah[i], Wh[i][0], az);
      az = MFMA16(Ah[i], Wl[i][0], az);
      az = MFMA16(Al[i], Wh[i][0], az);
      ar = MFMA16(Ah[i], Wh[i][1], ar);
      ar = MFMA16(Ah[i], Wl[i][1], ar);
      ar = MFMA16(Al[i], Wh[i][1], ar);
    }

    // ---- reduce az, ar (and amx, off the phase-2 critical path) ----
    red1[0][w][lane] = az;
    red1[1][w][lane] = ar;
    red1[2][w][lane] = amx;
    __syncthreads();                                   // S1
    f32x4 azF  = red1[0][0][lane] + red1[0][1][lane] + red1[0][2][lane] + red1[0][3][lane];
    f32x4 arF  = red1[1][0][lane] + red1[1][1][lane] + red1[1][2][lane] + red1[1][3][lane];
    f32x4 amxF = red1[2][0][lane] + red1[2][1][lane] + red1[2][2][lane] + red1[2][3][lane];

    // ---- pointwise 1: z, r, rh = r*h ; publish tagged rh (wave 0, fire&forget) ----
    float z[4];
    #pragma unroll
    for (int r = 0; r < 4; ++r) {
      z[r]     = 1.f / (1.f + __expf(-(azF[r] + bzj)));
      float rr = 1.f / (1.f + __expf(-(arF[r] + brj)));
      float rhv = rr * st[r];
      if (w == 0) {
        unsigned short sh, sl;
        splitf(rhv, sh, sl);
        int lane2 = (rb + r) + l2base;
        size_t eidx = ((size_t)kc2w*64 + lane2)*8 + e7;
        ull wd = ((ull)(unsigned)(t + 1) << 32)
               | (ull)(((unsigned)sh << 16) | (unsigned)sl);
        __hip_atomic_store(rt + (size_t)g*16384 + eidx, wd,
                           __ATOMIC_RELAXED, __HIP_MEMORY_SCOPE_AGENT);
      }
    }

    // ---- phase 2: wait + gather rh(t) (tag = t+1), m h-matmul ----
    spin16(rgrp, w, lane, (unsigned)(t + 1));
    bf16x8 Bh[8], Bl[8];
    while (__ballot(try_gather(Bh, Bl, rgrp + woff, (unsigned)(t + 1))) != ~0ull)
      __builtin_amdgcn_s_sleep(1);
    #pragma unroll
    for (int i = 0; i < 8; ++i) {
      amh = MFMA16(Bh[i], Wh[i][2], amh);
      amh = MFMA16(Bh[i], Wl[i][2], amh);
      amh = MFMA16(Bl[i], Wh[i][2], amh);
    }

    // ---- reduce amh ----
    red2[w][lane] = amh;
    __syncthreads();                                   // S2
    f32x4 amhF = red2[0][lane] + red2[1][lane] + red2[2][lane] + red2[3][lane];

    // ---- pointwise 2: h_tilde, h_new ; publish tagged h(t+1) (wave 0) ----
    const int obuf = buf ^ 1;
    float hnv[4];
    #pragma unroll
    for (int r = 0; r < 4; ++r) {
      float pm = amxF[r] + bmj + amhF[r];
      float e2 = __expf(2.f*pm);
      float htl = 1.f - 2.f/(e2 + 1.f);
      float hn = st[r] + z[r]*(htl - st[r]);
      st[r] = hn; hnv[r] = hn;
      if (w == 0) {
        unsigned short sh, sl;
        splitf(hn, sh, sl);
        int lane2 = (rb + r) + l2base;
        size_t eidx = ((size_t)kc2w*64 + lane2)*8 + e7;
        ull wd = ((ull)(unsigned)(t + 2) << 32)
               | (ull)(((unsigned)sh << 16) | (unsigned)sl);
        __hip_atomic_store(ht + (size_t)(g*2 + obuf)*16384 + eidx, wd,
                           __ATOMIC_RELAXED, __HIP_MEMORY_SCOPE_AGENT);
      }
    }

    // ---- output (off the inter-block critical path) ----
    if (w == 0) {
      #pragma unroll
      for (int r = 0; r < 4; ++r)
        __builtin_nontemporal_store(hnv[r],
            out + (size_t)(bb + r)*(SEQ*HID) + (size_t)t*HID + jc);
    }
  }
}

extern "C" void kernel_launch(void* const* d_in, const int* in_sizes, int n_in,
                              void* d_out, int out_size, void* d_ws, size_t ws_size,
                              hipStream_t stream) {
  const float* emb = (const float*)d_in[0];
  const float* h0  = (const float*)d_in[1];
  const float* Wz  = (const float*)d_in[2];
  const float* bz  = (const float*)d_in[3];
  const float* Wr  = (const float*)d_in[4];
  const float* br  = (const float*)d_in[5];
  const float* Wm  = (const float*)d_in[6];
  const float* bm  = (const float*)d_in[7];
  float* out = (float*)d_out;

  if (ws_size < (size_t)WS_END) return;

  char* ws = (char*)d_ws;
  ull*    htp = (ull*)(ws + WS_HT);
  ull*    rtp = (ull*)(ws + WS_RT);
  bf16x8* wph = (bf16x8*)(ws + WS_WHI);
  bf16x8* wpl = (bf16x8*)(ws + WS_WLO);

  hipMemsetAsync(ws, 0, WS_WHI, stream);          // zero ht + rt (tags != any target)
  prep_w<<<2304, 256, 0, stream>>>(Wz, Wr, Wm, wph, wpl);
  prep_h<<<32,   256, 0, stream>>>(h0, htp);
  gru_main<<<256, 256, 0, stream>>>(emb, bz, br, bm, h0, out,
                                    wph, wpl, htp, rtp);
}

// Round 4
// 10642.841 us; speedup vs baseline: 1.9482x; 1.4466x over previous
//
#include <hip/hip_runtime.h>
#include <cstdint>
#include <cstddef>

#define SEQ   512
#define BATCH 64
#define INDIM 512
#define HID   1024

typedef short bf16x8 __attribute__((ext_vector_type(8)));
typedef float f32x4  __attribute__((ext_vector_type(4)));
typedef unsigned long long ull;

#define MFMA16(A,B,C) __builtin_amdgcn_mfma_f32_16x16x32_bf16(A,B,C,0,0,0)

// ---- workspace layout (bytes) ----
// ht : [4 grp][2 buf][32 kc][8 e][64 lane2] u64  (tag<<32 | hi<<16 | lo)  1,048,576 B
// rt : [4 grp][32 kc][8 e][64 lane2] u64                                    524,288 B
// W_hi : [64 jb][48 kc][3 gate][64 lane][8] bf16                          9,437,184 B
// W_lo : same                                                             9,437,184 B
// NOTE lane2 innermost => consumer gather instruction (kc,e) is 512 B contiguous.
#define WS_HT  0
#define WS_RT  1048576
#define WS_WHI 1572864
#define WS_WLO (WS_WHI + 9437184)
#define WS_END (WS_WLO + 9437184)

__device__ __forceinline__ unsigned short f2bf(float f) {
  unsigned u = __float_as_uint(f);
  unsigned r = (u + 0x7fffu + ((u >> 16) & 1u)) >> 16;  // RNE
  return (unsigned short)r;
}
__device__ __forceinline__ float bf2f(unsigned short h) {
  return __uint_as_float(((unsigned)h) << 16);
}
__device__ __forceinline__ void splitf(float x, unsigned short& hi, unsigned short& lo) {
  unsigned short h = f2bf(x);
  float r = x - bf2f(h);          // exact
  hi = h; lo = f2bf(r);           // combined rel err ~2^-18
}

// ---------------- prep: pack weights (B-fragment order, hi+lo) ----------------
__global__ void prep_w(const float* __restrict__ Wz, const float* __restrict__ Wr,
                       const float* __restrict__ Wm,
                       bf16x8* __restrict__ wh, bf16x8* __restrict__ wl) {
  int n    = blockIdx.x * 256 + threadIdx.x;     // 589,824 threads
  int lane = n & 63;
  int m    = n >> 6;
  int g    = m % 3;
  int m2   = m / 3;
  int kc   = m2 % 48;
  int jb   = m2 / 48;
  const float* W = (g == 0) ? Wz : (g == 1) ? Wr : Wm;
  int k0 = kc*32 + ((lane >> 4) << 3);
  int nn = jb*16 + (lane & 15);
  bf16x8 vh, vl;
  #pragma unroll
  for (int j = 0; j < 8; ++j) {
    unsigned short a, b;
    splitf(W[(size_t)(k0 + j)*HID + nn], a, b);
    vh[j] = (short)a; vl[j] = (short)b;
  }
  wh[n] = vh; wl[n] = vl;
}

// ---------------- prep: pack init_h (tagged u64, tag=1) into buf 0 ----------------
// slot(b, col) = grp(b>>4) buf0 : [kc=col>>5][e=col&7][lane2=(b&15)+((col>>3)&3)*16]
__global__ void prep_h(const float* __restrict__ h0, ull* __restrict__ ht) {
  int n = blockIdx.x * 256 + threadIdx.x;        // 8192 threads
  int b = n >> 7;
  int j = (n & 127) << 3;                        // col base, multiple of 8 -> e=q
  const float* s = h0 + (size_t)b*HID + j;
  float4 f0 = ((const float4*)s)[0];
  float4 f1 = ((const float4*)s)[1];
  float v[8] = {f0.x,f0.y,f0.z,f0.w,f1.x,f1.y,f1.z,f1.w};
  int g     = b >> 4;
  int kc2   = j >> 5;
  int lane2 = (b & 15) + (((j >> 3) & 3) << 4);
  size_t base = (size_t)(g*2 + 0)*16384 + (size_t)kc2*512 + (size_t)lane2;
  #pragma unroll
  for (int q = 0; q < 8; ++q) {
    unsigned short a, c;
    splitf(v[q], a, c);
    ht[base + (size_t)q*64] = ((ull)1u << 32) | (ull)(((unsigned)a << 16) | (unsigned)c);
  }
}

// ---- constant-footprint spin: 16 sentinel words (16 lines) per wave ----
// Producer jb' sentinel (lane63, r=3): [kc=jb'>>1][e=7][lane2=(jb'&1)*32+31].
// Wave w's producers are jb' = 16w..16w+15; lane polls producer (lane&15).
__device__ __forceinline__ void spin16(const ull* __restrict__ gbase,
                                       int w, int lane, unsigned tgt) {
  int p = lane & 15;
  const ull* s = gbase + (size_t)((8*w + (p >> 1))*8 + 7)*64
                       + (size_t)(((p & 1) << 5) | 31);
  for (;;) {
    ull v = __hip_atomic_load(s, __ATOMIC_RELAXED, __HIP_MEMORY_SCOPE_AGENT);
    if (__ballot((unsigned)(v >> 32) >= tgt) == ~0ull) return;
    __builtin_amdgcn_s_sleep(1);
  }
}

// ---- full tagged gather of this wave's 8 A-fragments (hi+lo), verify tags ----
// base = group buffer + w*4096 + lane ; load (i,e) at +i*512 + e*64 (coalesced).
__device__ __forceinline__ bool try_gather(bf16x8* Fh, bf16x8* Fl,
                                           const ull* __restrict__ base,
                                           unsigned tgt) {
  bool ok = true;
  #pragma unroll
  for (int i = 0; i < 8; ++i) {
    ull v[8];
    #pragma unroll
    for (int e = 0; e < 8; ++e)
      v[e] = __hip_atomic_load(base + (size_t)i*512 + (size_t)e*64,
                               __ATOMIC_RELAXED, __HIP_MEMORY_SCOPE_AGENT);
    bf16x8 h8, l8;
    #pragma unroll
    for (int e = 0; e < 8; ++e) {
      ok &= ((unsigned)(v[e] >> 32) == tgt);
      unsigned pp = (unsigned)v[e];
      h8[e] = (short)(pp >> 16);
      l8[e] = (short)(pp & 0xffffu);
    }
    Fh[i] = h8; Fl[i] = l8;
  }
  return ok;
}

// ---------------- main persistent GRU kernel ----------------
// 256 blocks x 256 threads. blockIdx = g*64 + jb.
// Block (g,jb): batch rows [g*16,g*16+16), HID cols [jb*16,jb*16+16), full K.
// 4 waves K-split (8 kc each of the h-part); partials reduced via LDS.
// Cross-block exchange: self-validating tagged u64 words, fire-and-forget
// producers (no release fences), sentinel spin + coalesced verify-gather.
__global__ __launch_bounds__(256, 1)
void gru_main(const float* __restrict__ emb,
              const float* __restrict__ bz, const float* __restrict__ br,
              const float* __restrict__ bm, const float* __restrict__ init_h,
              float* __restrict__ out,
              const bf16x8* __restrict__ wh_all, const bf16x8* __restrict__ wl_all,
              ull* __restrict__ ht, ull* __restrict__ rt)
{
  const int tid  = threadIdx.x;
  const int w    = tid >> 6;
  const int lane = tid & 63;
  const int jb   = blockIdx.x & 63;
  const int g    = blockIdx.x >> 6;
  const int c    = lane & 15;
  const int q    = lane >> 4;
  const int jc   = jb*16 + c;             // C/D col
  const int rb   = q << 2;                // C/D row base within 16-row tile
  const int bb   = g*16 + rb;             // global batch row base

  const float bzj = bz[jc], brj = br[jc], bmj = bm[jc];
  float st[4];
  #pragma unroll
  for (int r = 0; r < 4; ++r) st[r] = init_h[(size_t)(bb + r)*HID + jc];

  __shared__ f32x4 red1[3][4][64];   // az, ar, amx partials
  __shared__ f32x4 red2[4][64];      // amh partials

  // ---- preload this wave's h-part W slice into registers (48 frags) ----
  const bf16x8* whB = wh_all + ((size_t)jb*48*3)*64 + lane;
  const bf16x8* wlB = wl_all + ((size_t)jb*48*3)*64 + lane;
  bf16x8 Wh[8][3], Wl[8][3];
  #pragma unroll
  for (int i = 0; i < 8; ++i) {
    int kc = 16 + w*8 + i;
    #pragma unroll
    for (int gt = 0; gt < 3; ++gt) {
      Wh[i][gt] = whB[(size_t)(kc*3 + gt)*64];
      Wl[i][gt] = wlB[(size_t)(kc*3 + gt)*64];
    }
  }

  // publish base (owner side): words r=0..3 are CONSECUTIVE addresses
  const size_t pub_off = (size_t)(jb >> 1)*512 + (size_t)(c & 7)*64
                       + (size_t)((jb & 1)*32 + (c >> 3)*16 + q*4);

  // group-level publish-buffer bases and this wave's gather offset
  const ull* hgrp0 = ht + (size_t)(g*2 + 0)*16384;
  const ull* hgrp1 = hgrp0 + 16384;
  const ull* rgrp  = rt + (size_t)g*16384;
  const size_t woff = (size_t)w*4096 + (size_t)lane;

  // e-part A source: lane holds emb[t][g*16+c][kce*32+q*8 .. +7]
  const float* ebase = emb + (size_t)(g*16 + c)*INDIM + (q << 3);

  for (int t = 0; t < SEQ; ++t) {
    f32x4 az  = {0.f,0.f,0.f,0.f};
    f32x4 ar  = {0.f,0.f,0.f,0.f};
    f32x4 amx = {0.f,0.f,0.f,0.f};
    f32x4 amh = {0.f,0.f,0.f,0.f};

    // ---- e-part (x-projections, K-slice kce = w*4..w*4+3): overlaps h wait ----
    const float* et = ebase + (size_t)t*(BATCH*INDIM);
    #pragma unroll
    for (int qq = 0; qq < 4; ++qq) {
      int kce = w*4 + qq;
      const float* s = et + kce*32;
      float4 f0 = ((const float4*)s)[0];
      float4 f1 = ((const float4*)s)[1];
      float v[8] = {f0.x,f0.y,f0.z,f0.w,f1.x,f1.y,f1.z,f1.w};
      bf16x8 eh, el;
      #pragma unroll
      for (int j = 0; j < 8; ++j) {
        unsigned short a, b;
        splitf(v[j], a, b);
        eh[j] = (short)a; el[j] = (short)b;
      }
      bf16x8 wzh = whB[(size_t)(kce*3+0)*64], wzl = wlB[(size_t)(kce*3+0)*64];
      bf16x8 wrh = whB[(size_t)(kce*3+1)*64], wrl = wlB[(size_t)(kce*3+1)*64];
      bf16x8 wmh = whB[(size_t)(kce*3+2)*64], wml = wlB[(size_t)(kce*3+2)*64];
      az  = MFMA16(eh, wzh, az);  az  = MFMA16(eh, wzl, az);  az  = MFMA16(el, wzh, az);
      ar  = MFMA16(eh, wrh, ar);  ar  = MFMA16(eh, wrl, ar);  ar  = MFMA16(el, wrh, ar);
      amx = MFMA16(eh, wmh, amx); amx = MFMA16(eh, wml, amx); amx = MFMA16(el, wmh, amx);
    }

    // ---- phase 1: wait + gather h(t) (tag = t+1), z/r h-matmul over K-slice ----
    const int buf = t & 1;
    const ull* gb = buf ? hgrp1 : hgrp0;
    spin16(gb, w, lane, (unsigned)(t + 1));
    bf16x8 Ah[8], Al[8];
    while (__ballot(try_gather(Ah, Al, gb + woff, (unsigned)(t + 1))) != ~0ull)
      __builtin_amdgcn_s_sleep(1);
    #pragma unroll
    for (int i = 0; i < 8; ++i) {
      az = MFMA16(Ah[i], Wh[i][0], az);
      az = MFMA16(Ah[i], Wl[i][0], az);
      az = MFMA16(Al[i], Wh[i][0], az);
      ar = MFMA16(Ah[i], Wh[i][1], ar);
      ar = MFMA16(Ah[i], Wl[i][1], ar);
      ar = MFMA16(Al[i], Wh[i][1], ar);
    }

    // ---- reduce az, ar (and amx, off the phase-2 critical path) ----
    red1[0][w][lane] = az;
    red1[1][w][lane] = ar;
    red1[2][w][lane] = amx;
    __syncthreads();                                   // S1
    f32x4 azF  = red1[0][0][lane] + red1[0][1][lane] + red1[0][2][lane] + red1[0][3][lane];
    f32x4 arF  = red1[1][0][lane] + red1[1][1][lane] + red1[1][2][lane] + red1[1][3][lane];
    f32x4 amxF = red1[2][0][lane] + red1[2][1][lane] + red1[2][2][lane] + red1[2][3][lane];

    // ---- pointwise 1: z, r, rh = r*h ; publish tagged rh (wave 0, fire&forget) ----
    float z[4];
    #pragma unroll
    for (int r = 0; r < 4; ++r) {
      z[r]     = 1.f / (1.f + __expf(-(azF[r] + bzj)));
      float rr = 1.f / (1.f + __expf(-(arF[r] + brj)));
      float rhv = rr * st[r];
      if (w == 0) {
        unsigned short sh, sl;
        splitf(rhv, sh, sl);
        ull wd = ((ull)(unsigned)(t + 1) << 32)
               | (ull)(((unsigned)sh << 16) | (unsigned)sl);
        __hip_atomic_store(rt + (size_t)g*16384 + pub_off + r, wd,
                           __ATOMIC_RELAXED, __HIP_MEMORY_SCOPE_AGENT);
      }
    }

    // ---- phase 2: wait + gather rh(t) (tag = t+1), m h-matmul ----
    spin16(rgrp, w, lane, (unsigned)(t + 1));
    bf16x8 Bh[8], Bl[8];
    while (__ballot(try_gather(Bh, Bl, rgrp + woff, (unsigned)(t + 1))) != ~0ull)
      __builtin_amdgcn_s_sleep(1);
    #pragma unroll
    for (int i = 0; i < 8; ++i) {
      amh = MFMA16(Bh[i], Wh[i][2], amh);
      amh = MFMA16(Bh[i], Wl[i][2], amh);
      amh = MFMA16(Bl[i], Wh[i][2], amh);
    }

    // ---- reduce amh ----
    red2[w][lane] = amh;
    __syncthreads();                                   // S2
    f32x4 amhF = red2[0][lane] + red2[1][lane] + red2[2][lane] + red2[3][lane];

    // ---- pointwise 2: h_tilde, h_new ; publish tagged h(t+1) (wave 0) ----
    const int obuf = buf ^ 1;
    ull* hout = ht + (size_t)(g*2 + obuf)*16384 + pub_off;
    float hnv[4];
    #pragma unroll
    for (int r = 0; r < 4; ++r) {
      float pm = amxF[r] + bmj + amhF[r];
      float e2 = __expf(2.f*pm);
      float htl = 1.f - 2.f/(e2 + 1.f);
      float hn = st[r] + z[r]*(htl - st[r]);
      st[r] = hn; hnv[r] = hn;
      if (w == 0) {
        unsigned short sh, sl;
        splitf(hn, sh, sl);
        ull wd = ((ull)(unsigned)(t + 2) << 32)
               | (ull)(((unsigned)sh << 16) | (unsigned)sl);
        __hip_atomic_store(hout + r, wd,
                           __ATOMIC_RELAXED, __HIP_MEMORY_SCOPE_AGENT);
      }
    }

    // ---- output (off the inter-block critical path) ----
    if (w == 0) {
      #pragma unroll
      for (int r = 0; r < 4; ++r)
        __builtin_nontemporal_store(hnv[r],
            out + (size_t)(bb + r)*(SEQ*HID) + (size_t)t*HID + jc);
    }
  }
}

extern "C" void kernel_launch(void* const* d_in, const int* in_sizes, int n_in,
                              void* d_out, int out_size, void* d_ws, size_t ws_size,
                              hipStream_t stream) {
  const float* emb = (const float*)d_in[0];
  const float* h0  = (const float*)d_in[1];
  const float* Wz  = (const float*)d_in[2];
  const float* bz  = (const float*)d_in[3];
  const float* Wr  = (const float*)d_in[4];
  const float* br  = (const float*)d_in[5];
  const float* Wm  = (const float*)d_in[6];
  const float* bm  = (const float*)d_in[7];
  float* out = (float*)d_out;

  if (ws_size < (size_t)WS_END) return;

  char* ws = (char*)d_ws;
  ull*    htp = (ull*)(ws + WS_HT);
  ull*    rtp = (ull*)(ws + WS_RT);
  bf16x8* wph = (bf16x8*)(ws + WS_WHI);
  bf16x8* wpl = (bf16x8*)(ws + WS_WLO);

  hipMemsetAsync(ws, 0, WS_WHI, stream);          // zero ht + rt (tags != any target)
  prep_w<<<2304, 256, 0, stream>>>(Wz, Wr, Wm, wph, wpl);
  prep_h<<<32,   256, 0, stream>>>(h0, htp);
  gru_main<<<256, 256, 0, stream>>>(emb, bz, br, bm, h0, out,
                                    wph, wpl, htp, rtp);
}

// Round 5
// 9597.536 us; speedup vs baseline: 2.1604x; 1.1089x over previous
//
#include <hip/hip_runtime.h>
#include <cstdint>
#include <cstddef>

#define SEQ   512
#define BATCH 64
#define INDIM 512
#define HID   1024

typedef short bf16x8 __attribute__((ext_vector_type(8)));
typedef float f32x4  __attribute__((ext_vector_type(4)));
typedef unsigned long long ull;
typedef unsigned int u32;

#define MFMA16(A,B,C) __builtin_amdgcn_mfma_f32_16x16x32_bf16(A,B,C,0,0,0)

// ---- workspace layout (bytes) ----
// fh : [4 grp][64 jb][16] u32 flag lines                                16,384 B
// fr : same                                                             16,384 B
// hp : [4 grp][2 buf][32 kc][64 lane][8 e] u32 (hi<<16|lo)             524,288 B
// rp : [4 grp][32 kc][64 lane][8 e] u32                                262,144 B
// W_hi : [64 jb][48 kc][3 gate][64 lane][8] bf16                     9,437,184 B
// W_lo : same                                                        9,437,184 B
#define WS_FH  0
#define WS_FR  16384
#define WS_HP  32768
#define WS_RP  (WS_HP + 524288)
#define WS_WHI (WS_RP + 262144)
#define WS_WLO (WS_WHI + 9437184)
#define WS_END (WS_WLO + 9437184)   // 19,693,568 B (ws proven >= 43 MB)

__device__ __forceinline__ unsigned short f2bf(float f) {
  unsigned u = __float_as_uint(f);
  unsigned r = (u + 0x7fffu + ((u >> 16) & 1u)) >> 16;  // RNE
  return (unsigned short)r;
}
__device__ __forceinline__ float bf2f(unsigned short h) {
  return __uint_as_float(((unsigned)h) << 16);
}
__device__ __forceinline__ void splitf(float x, unsigned short& hi, unsigned short& lo) {
  unsigned short h = f2bf(x);
  float r = x - bf2f(h);          // exact
  hi = h; lo = f2bf(r);           // combined rel err ~2^-18
}

// ---------------- prep: pack weights (B-fragment order, hi+lo) ----------------
__global__ void prep_w(const float* __restrict__ Wz, const float* __restrict__ Wr,
                       const float* __restrict__ Wm,
                       bf16x8* __restrict__ wh, bf16x8* __restrict__ wl) {
  int n    = blockIdx.x * 256 + threadIdx.x;     // 589,824 threads
  int lane = n & 63;
  int m    = n >> 6;
  int g    = m % 3;
  int m2   = m / 3;
  int kc   = m2 % 48;
  int jb   = m2 / 48;
  const float* W = (g == 0) ? Wz : (g == 1) ? Wr : Wm;
  int k0 = kc*32 + ((lane >> 4) << 3);
  int nn = jb*16 + (lane & 15);
  bf16x8 vh, vl;
  #pragma unroll
  for (int j = 0; j < 8; ++j) {
    unsigned short a, b;
    splitf(W[(size_t)(k0 + j)*HID + nn], a, b);
    vh[j] = (short)a; vl[j] = (short)b;
  }
  wh[n] = vh; wl[n] = vl;
}

// ---------------- prep: pack init_h (packed u32) into buf 0 ----------------
__global__ void prep_h(const float* __restrict__ h0, u32* __restrict__ hp) {
  int n = blockIdx.x * 256 + threadIdx.x;        // 8192 threads
  int b = n >> 7;
  int j = (n & 127) << 3;
  const float* s = h0 + (size_t)b*HID + j;
  float4 f0 = ((const float4*)s)[0];
  float4 f1 = ((const float4*)s)[1];
  float v[8] = {f0.x,f0.y,f0.z,f0.w,f1.x,f1.y,f1.z,f1.w};
  int g     = b >> 4;
  int kc2   = j >> 5;
  int lane2 = (b & 15) + (((j >> 3) & 3) << 4);
  size_t base = (size_t)g*32768 + ((size_t)kc2*64 + lane2)*8;  // buf 0
  #pragma unroll
  for (int q = 0; q < 8; ++q) {
    unsigned short a, c;
    splitf(v[q], a, c);
    hp[base + q] = ((u32)a << 16) | (u32)c;
  }
}

// per-wave wait: 64 lanes poll 16 distinct flag lines (4 lanes/flag), exit on ballot
__device__ __forceinline__ void waitf(const u32* f, unsigned tgt) {
  for (;;) {
    unsigned v = __hip_atomic_load(f, __ATOMIC_RELAXED, __HIP_MEMORY_SCOPE_AGENT);
    if (__ballot(v >= tgt) == ~0ull) return;
    __builtin_amdgcn_s_sleep(1);
  }
}

// load 8 A-fragments (hi+lo) from packed-u32 buffer; frag i at base32 + i*512,
// 8 consecutive u32 per lane (32 B) -> 4 u64 agent-scope loads per frag.
__device__ __forceinline__ void loadfrags(bf16x8* Fh, bf16x8* Fl,
                                          const u32* __restrict__ base32) {
  #pragma unroll
  for (int i = 0; i < 8; ++i) {
    const ull* p = (const ull*)(base32 + (size_t)i*512);
    ull u0 = __hip_atomic_load(p + 0, __ATOMIC_RELAXED, __HIP_MEMORY_SCOPE_AGENT);
    ull u1 = __hip_atomic_load(p + 1, __ATOMIC_RELAXED, __HIP_MEMORY_SCOPE_AGENT);
    ull u2 = __hip_atomic_load(p + 2, __ATOMIC_RELAXED, __HIP_MEMORY_SCOPE_AGENT);
    ull u3 = __hip_atomic_load(p + 3, __ATOMIC_RELAXED, __HIP_MEMORY_SCOPE_AGENT);
    u32 wv[8] = { (u32)u0, (u32)(u0 >> 32), (u32)u1, (u32)(u1 >> 32),
                  (u32)u2, (u32)(u2 >> 32), (u32)u3, (u32)(u3 >> 32) };
    bf16x8 h8, l8;
    #pragma unroll
    for (int e = 0; e < 8; ++e) {
      h8[e] = (short)(wv[e] >> 16);
      l8[e] = (short)(wv[e] & 0xffffu);
    }
    Fh[i] = h8; Fl[i] = l8;
  }
}

// ---------------- main persistent GRU kernel ----------------
// 256 blocks x 256 threads. blockIdx = g*64 + jb.
// Block (g,jb): batch rows [g*16,g*16+16), HID cols [jb*16,jb*16+16), full K.
// 4 waves K-split (8 kc each of the h-part); partials reduced via LDS.
// Exchange: packed-u32 words, per-producer flag + release (round-0 protocol).
__global__ __launch_bounds__(256, 1)
void gru_main(const float* __restrict__ emb,
              const float* __restrict__ bz, const float* __restrict__ br,
              const float* __restrict__ bm, const float* __restrict__ init_h,
              float* __restrict__ out,
              const bf16x8* __restrict__ wh_all, const bf16x8* __restrict__ wl_all,
              u32* __restrict__ hp, u32* __restrict__ rp,
              u32* __restrict__ fh, u32* __restrict__ fr)
{
  const int tid  = threadIdx.x;
  const int w    = tid >> 6;
  const int lane = tid & 63;
  const int jb   = blockIdx.x & 63;
  const int g    = blockIdx.x >> 6;
  const int c    = lane & 15;
  const int q    = lane >> 4;
  const int jc   = jb*16 + c;             // C/D col
  const int rb   = q << 2;                // C/D row base within 16-row tile
  const int bb   = g*16 + rb;             // global batch row base

  u32* fh_g = fh + g*1024;
  u32* fr_g = fr + g*1024;
  const u32* fh_w = fh_g + ((w*16 + c) << 4);   // this wave's 16 producers
  const u32* fr_w = fr_g + ((w*16 + c) << 4);

  const float bzj = bz[jc], brj = br[jc], bmj = bm[jc];
  float st[4];
  #pragma unroll
  for (int r = 0; r < 4; ++r) st[r] = init_h[(size_t)(bb + r)*HID + jc];

  __shared__ f32x4  red1[3][4][64];   // az, ar, amx partials (12 KB)
  __shared__ f32x4  red2[4][64];      // amh partials (4 KB)
  __shared__ bf16x8 ewS[96][64];      // e-part weights: [hl*48 + kce*3 + gt][lane] (96 KB)

  // ---- preload e-part weights into LDS (once) ----
  for (int i = tid; i < 6144; i += 256) {
    int l = i & 63, row = i >> 6;             // row 0..95
    int hl = row / 48, rr2 = row % 48;        // rr2 = kce*3 + gt
    const bf16x8* src = (hl ? wl_all : wh_all) + ((size_t)jb*144 + rr2)*64 + l;
    ewS[row][l] = *src;
  }

  // ---- preload this wave's h-part W slice into registers (48 frags) ----
  const bf16x8* whB = wh_all + ((size_t)jb*144)*64 + lane;
  const bf16x8* wlB = wl_all + ((size_t)jb*144)*64 + lane;
  bf16x8 Wh[8][3], Wl[8][3];
  #pragma unroll
  for (int i = 0; i < 8; ++i) {
    int kc = 16 + w*8 + i;
    #pragma unroll
    for (int gt = 0; gt < 3; ++gt) {
      Wh[i][gt] = whB[(size_t)(kc*3 + gt)*64];
      Wl[i][gt] = wlB[(size_t)(kc*3 + gt)*64];
    }
  }
  __syncthreads();   // ewS ready

  // publish base (owner side), u32 index; r stride = 8 (lane2+1)
  const int kc2w   = jc >> 5;
  const int l2base = ((jc & 31) >> 3) << 4;
  const int e7     = jc & 7;
  const size_t pub_base = ((size_t)kc2w*64 + (rb + l2base))*8 + e7;

  // gather bases (u32 granularity): frag i of wave w at + i*512, lane*8 inner
  const u32* hgrp0 = hp + (size_t)g*32768;            // buf 0
  const u32* hgrp1 = hgrp0 + 16384;                   // buf 1
  const u32* rgrp  = rp + (size_t)g*16384;
  const size_t woff = (size_t)w*4096 + (size_t)lane*8;

  // e-part A source: lane holds emb[t][g*16+c][kce*32+q*8 .. +7]
  const float* ebase = emb + (size_t)(g*16 + c)*INDIM + (q << 3);

  for (int t = 0; t < SEQ; ++t) {
    f32x4 az  = {0.f,0.f,0.f,0.f};
    f32x4 ar  = {0.f,0.f,0.f,0.f};
    f32x4 amx = {0.f,0.f,0.f,0.f};
    f32x4 amh = {0.f,0.f,0.f,0.f};

    // ---- e-part (x-projections, K-slice kce = w*4..w*4+3): overlaps h wait ----
    const float* et = ebase + (size_t)t*(BATCH*INDIM);
    #pragma unroll
    for (int qq = 0; qq < 4; ++qq) {
      int kce = w*4 + qq;
      const float* s = et + kce*32;
      float4 f0 = ((const float4*)s)[0];
      float4 f1 = ((const float4*)s)[1];
      float v[8] = {f0.x,f0.y,f0.z,f0.w,f1.x,f1.y,f1.z,f1.w};
      bf16x8 eh, el;
      #pragma unroll
      for (int j = 0; j < 8; ++j) {
        unsigned short a, b;
        splitf(v[j], a, b);
        eh[j] = (short)a; el[j] = (short)b;
      }
      int rowz = kce*3;
      bf16x8 wzh = ewS[rowz+0][lane], wzl = ewS[48+rowz+0][lane];
      bf16x8 wrh = ewS[rowz+1][lane], wrl = ewS[48+rowz+1][lane];
      bf16x8 wmh = ewS[rowz+2][lane], wml = ewS[48+rowz+2][lane];
      az  = MFMA16(eh, wzh, az);  az  = MFMA16(eh, wzl, az);  az  = MFMA16(el, wzh, az);
      ar  = MFMA16(eh, wrh, ar);  ar  = MFMA16(eh, wrl, ar);  ar  = MFMA16(el, wrh, ar);
      amx = MFMA16(eh, wmh, amx); amx = MFMA16(eh, wml, amx); amx = MFMA16(el, wmh, amx);
    }

    // ---- phase 1: wait producers' h(t), gather, z/r h-matmul over K-slice ----
    const int buf = t & 1;
    if (t > 0) waitf(fh_w, (unsigned)t);
    bf16x8 Ah[8], Al[8];
    loadfrags(Ah, Al, (buf ? hgrp1 : hgrp0) + woff);
    #pragma unroll
    for (int i = 0; i < 8; ++i) {
      az = MFMA16(Ah[i], Wh[i][0], az);
      az = MFMA16(Ah[i], Wl[i][0], az);
      az = MFMA16(Al[i], Wh[i][0], az);
      ar = MFMA16(Ah[i], Wh[i][1], ar);
      ar = MFMA16(Ah[i], Wl[i][1], ar);
      ar = MFMA16(Al[i], Wh[i][1], ar);
    }

    // ---- reduce az, ar (and amx, off the phase-2 critical path) ----
    red1[0][w][lane] = az;
    red1[1][w][lane] = ar;
    red1[2][w][lane] = amx;
    __syncthreads();                                   // S1
    f32x4 azF  = red1[0][0][lane] + red1[0][1][lane] + red1[0][2][lane] + red1[0][3][lane];
    f32x4 arF  = red1[1][0][lane] + red1[1][1][lane] + red1[1][2][lane] + red1[1][3][lane];
    f32x4 amxF = red1[2][0][lane] + red1[2][1][lane] + red1[2][2][lane] + red1[2][3][lane];

    // ---- pointwise 1 (wave 0 only): r, rh = r*h ; publish FIRST, z deferred ----
    if (w == 0) {
      u32* dst = rp + (size_t)g*16384 + pub_base;
      #pragma unroll
      for (int r = 0; r < 4; ++r) {
        float rr  = 1.f / (1.f + __expf(-(arF[r] + brj)));
        float rhv = rr * st[r];
        unsigned short sh, sl;
        splitf(rhv, sh, sl);
        __hip_atomic_store(dst + (size_t)r*8, ((u32)sh << 16) | (u32)sl,
                           __ATOMIC_RELAXED, __HIP_MEMORY_SCOPE_AGENT);
      }
    }
    if (tid == 0)   // release: wave-level vmcnt drain covers all wave-0 stores
      __hip_atomic_store(fr_g + (jb << 4), (unsigned)(t + 1),
                         __ATOMIC_RELEASE, __HIP_MEMORY_SCOPE_AGENT);

    // ---- phase 2: wait producers' rh(t), gather, m h-matmul ----
    waitf(fr_w, (unsigned)(t + 1));
    bf16x8 Bh[8], Bl[8];
    loadfrags(Bh, Bl, rgrp + woff);
    // z-gate computed here: VALU overlaps the gather's load latency
    float z[4];
    #pragma unroll
    for (int r = 0; r < 4; ++r)
      z[r] = 1.f / (1.f + __expf(-(azF[r] + bzj)));
    #pragma unroll
    for (int i = 0; i < 8; ++i) {
      amh = MFMA16(Bh[i], Wh[i][2], amh);
      amh = MFMA16(Bh[i], Wl[i][2], amh);
      amh = MFMA16(Bl[i], Wh[i][2], amh);
    }

    // ---- reduce amh ----
    red2[w][lane] = amh;
    __syncthreads();                                   // S2
    f32x4 amhF = red2[0][lane] + red2[1][lane] + red2[2][lane] + red2[3][lane];

    // ---- pointwise 2: h_tilde, h_new ; publish h(t+1) (wave 0), release ----
    const int obuf = buf ^ 1;
    u32* hdst = hp + (size_t)g*32768 + (size_t)obuf*16384 + pub_base;
    float hnv[4];
    #pragma unroll
    for (int r = 0; r < 4; ++r) {
      float pm = amxF[r] + bmj + amhF[r];
      float e2 = __expf(2.f*pm);
      float htl = 1.f - 2.f/(e2 + 1.f);
      float hn = st[r] + z[r]*(htl - st[r]);
      st[r] = hn; hnv[r] = hn;
      if (w == 0) {
        unsigned short sh, sl;
        splitf(hn, sh, sl);
        __hip_atomic_store(hdst + (size_t)r*8, ((u32)sh << 16) | (u32)sl,
                           __ATOMIC_RELAXED, __HIP_MEMORY_SCOPE_AGENT);
      }
    }
    if (tid == 0)
      __hip_atomic_store(fh_g + (jb << 4), (unsigned)(t + 1),
                         __ATOMIC_RELEASE, __HIP_MEMORY_SCOPE_AGENT);

    // ---- output on wave 1: keeps HBM store drains off wave 0's release path ----
    if (w == 1) {
      #pragma unroll
      for (int r = 0; r < 4; ++r)
        __builtin_nontemporal_store(hnv[r],
            out + (size_t)(bb + r)*(SEQ*HID) + (size_t)t*HID + jc);
    }
  }
}

extern "C" void kernel_launch(void* const* d_in, const int* in_sizes, int n_in,
                              void* d_out, int out_size, void* d_ws, size_t ws_size,
                              hipStream_t stream) {
  const float* emb = (const float*)d_in[0];
  const float* h0  = (const float*)d_in[1];
  const float* Wz  = (const float*)d_in[2];
  const float* bz  = (const float*)d_in[3];
  const float* Wr  = (const float*)d_in[4];
  const float* br  = (const float*)d_in[5];
  const float* Wm  = (const float*)d_in[6];
  const float* bm  = (const float*)d_in[7];
  float* out = (float*)d_out;

  if (ws_size < (size_t)WS_END) return;

  char* ws = (char*)d_ws;
  u32*    fhp = (u32*)(ws + WS_FH);
  u32*    frp = (u32*)(ws + WS_FR);
  u32*    hpp = (u32*)(ws + WS_HP);
  u32*    rpp = (u32*)(ws + WS_RP);
  bf16x8* wph = (bf16x8*)(ws + WS_WHI);
  bf16x8* wpl = (bf16x8*)(ws + WS_WLO);

  hipMemsetAsync(ws, 0, 32768, stream);                     // zero both flag arrays
  prep_w<<<2304, 256, 0, stream>>>(Wz, Wr, Wm, wph, wpl);
  prep_h<<<32,   256, 0, stream>>>(h0, hpp);
  gru_main<<<256, 256, 0, stream>>>(emb, bz, br, bm, h0, out,
                                    wph, wpl, hpp, rpp, fhp, frp);
}

// Round 6
// 4507.742 us; speedup vs baseline: 4.5998x; 2.1291x over previous
//
#include <hip/hip_runtime.h>
#include <cstdint>
#include <cstddef>

#define SEQ   512
#define BATCH 64
#define INDIM 512
#define HID   1024

typedef short bf16x8 __attribute__((ext_vector_type(8)));
typedef float f32x4  __attribute__((ext_vector_type(4)));
typedef unsigned long long ull;
typedef unsigned int u32;

#define MFMA16(A,B,C) __builtin_amdgcn_mfma_f32_16x16x32_bf16(A,B,C,0,0,0)

// ---- workspace layout (bytes) ----
// fh : [4 grp][64 jb][16] u32 flag lines                                16,384 B
// fr : same                                                             16,384 B
// hp : [4 grp][2 buf][32 kc][8 e][64 lane2] u32 (hi<<16|lo)            524,288 B
// rp : [4 grp][32 kc][8 e][64 lane2] u32                               262,144 B
// W_hi : [64 jb][48 kc][3 gate][64 lane][8] bf16                     9,437,184 B
// W_lo : same                                                        9,437,184 B
// lane2 innermost => consumer gather instr (kc,e) is 256 B contiguous;
// producer's 4 r-values are CONSECUTIVE u32 => two 8-B stores.
#define WS_FH  0
#define WS_FR  16384
#define WS_HP  32768
#define WS_RP  (WS_HP + 524288)
#define WS_WHI (WS_RP + 262144)
#define WS_WLO (WS_WHI + 9437184)
#define WS_END (WS_WLO + 9437184)   // 19,693,568 B

__device__ __forceinline__ unsigned short f2bf(float f) {
  unsigned u = __float_as_uint(f);
  unsigned r = (u + 0x7fffu + ((u >> 16) & 1u)) >> 16;  // RNE
  return (unsigned short)r;
}
__device__ __forceinline__ float bf2f(unsigned short h) {
  return __uint_as_float(((unsigned)h) << 16);
}
__device__ __forceinline__ void splitf(float x, unsigned short& hi, unsigned short& lo) {
  unsigned short h = f2bf(x);
  float r = x - bf2f(h);          // exact
  hi = h; lo = f2bf(r);           // combined rel err ~2^-18
}

// ---------------- prep: pack weights (B-fragment order, hi+lo) ----------------
__global__ void prep_w(const float* __restrict__ Wz, const float* __restrict__ Wr,
                       const float* __restrict__ Wm,
                       bf16x8* __restrict__ wh, bf16x8* __restrict__ wl) {
  int n    = blockIdx.x * 256 + threadIdx.x;     // 589,824 threads
  int lane = n & 63;
  int m    = n >> 6;
  int g    = m % 3;
  int m2   = m / 3;
  int kc   = m2 % 48;
  int jb   = m2 / 48;
  const float* W = (g == 0) ? Wz : (g == 1) ? Wr : Wm;
  int k0 = kc*32 + ((lane >> 4) << 3);
  int nn = jb*16 + (lane & 15);
  bf16x8 vh, vl;
  #pragma unroll
  for (int j = 0; j < 8; ++j) {
    unsigned short a, b;
    splitf(W[(size_t)(k0 + j)*HID + nn], a, b);
    vh[j] = (short)a; vl[j] = (short)b;
  }
  wh[n] = vh; wl[n] = vl;
}

// ---------------- prep: pack init_h (packed u32) into buf 0 ----------------
// slot(b,col) = grp(b>>4) buf0 : [kc=col>>5][e=col&7][lane2=(b&15)+((col>>3)&3)*16]
__global__ void prep_h(const float* __restrict__ h0, u32* __restrict__ hp) {
  int n = blockIdx.x * 256 + threadIdx.x;        // 8192 threads
  int b = n >> 7;
  int j = (n & 127) << 3;                        // col base, e = q below
  const float* s = h0 + (size_t)b*HID + j;
  float4 f0 = ((const float4*)s)[0];
  float4 f1 = ((const float4*)s)[1];
  float v[8] = {f0.x,f0.y,f0.z,f0.w,f1.x,f1.y,f1.z,f1.w};
  int g     = b >> 4;
  int kc2   = j >> 5;
  int lane2 = (b & 15) + (((j >> 3) & 3) << 4);
  size_t base = (size_t)g*32768 + (size_t)kc2*512 + (size_t)lane2;  // buf 0
  #pragma unroll
  for (int q = 0; q < 8; ++q) {
    unsigned short a, c;
    splitf(v[q], a, c);
    hp[base + (size_t)q*64] = ((u32)a << 16) | (u32)c;
  }
}

// per-wave wait: 64 lanes poll 16 distinct flag lines (4 lanes/flag), exit on ballot
__device__ __forceinline__ void waitf(const u32* f, unsigned tgt) {
  for (;;) {
    unsigned v = __hip_atomic_load(f, __ATOMIC_RELAXED, __HIP_MEMORY_SCOPE_AGENT);
    if (__ballot(v >= tgt) == ~0ull) return;
    __builtin_amdgcn_s_sleep(1);
  }
}

// load 8 A-fragments (hi+lo); frag i at base + i*512, element e at + e*64,
// lane innermost => every load instruction is 256 B contiguous across the wave.
__device__ __forceinline__ void loadfrags(bf16x8* Fh, bf16x8* Fl,
                                          const u32* __restrict__ base32) {
  #pragma unroll
  for (int i = 0; i < 8; ++i) {
    u32 wv[8];
    #pragma unroll
    for (int e = 0; e < 8; ++e)
      wv[e] = __hip_atomic_load(base32 + (size_t)i*512 + (size_t)e*64,
                                __ATOMIC_RELAXED, __HIP_MEMORY_SCOPE_AGENT);
    bf16x8 h8, l8;
    #pragma unroll
    for (int e = 0; e < 8; ++e) {
      h8[e] = (short)(wv[e] >> 16);
      l8[e] = (short)(wv[e] & 0xffffu);
    }
    Fh[i] = h8; Fl[i] = l8;
  }
}

// ---------------- main persistent GRU kernel ----------------
// 256 blocks x 256 threads. blockIdx = g*64 + jb.
// Block (g,jb): batch rows [g*16,g*16+16), HID cols [jb*16,jb*16+16), full K.
// 4 waves K-split (8 kc each of the h-part); partials reduced via LDS.
// Exchange: packed-u32, per-producer flag; flag ordered by explicit
// s_waitcnt vmcnt(0) + RELAXED store (avoids agent-release's L2 writeback).
__global__ __launch_bounds__(256, 1)
void gru_main(const float* __restrict__ emb,
              const float* __restrict__ bz, const float* __restrict__ br,
              const float* __restrict__ bm, const float* __restrict__ init_h,
              float* __restrict__ out,
              const bf16x8* __restrict__ wh_all, const bf16x8* __restrict__ wl_all,
              u32* __restrict__ hp, u32* __restrict__ rp,
              u32* __restrict__ fh, u32* __restrict__ fr)
{
  const int tid  = threadIdx.x;
  const int w    = tid >> 6;
  const int lane = tid & 63;
  const int jb   = blockIdx.x & 63;
  const int g    = blockIdx.x >> 6;
  const int c    = lane & 15;
  const int q    = lane >> 4;
  const int jc   = jb*16 + c;             // C/D col
  const int rb   = q << 2;                // C/D row base within 16-row tile
  const int bb   = g*16 + rb;             // global batch row base

  u32* fh_g = fh + g*1024;
  u32* fr_g = fr + g*1024;
  const u32* fh_w = fh_g + ((w*16 + c) << 4);   // this wave's 16 producers
  const u32* fr_w = fr_g + ((w*16 + c) << 4);

  const float bzj = bz[jc], brj = br[jc], bmj = bm[jc];
  float st[4];
  #pragma unroll
  for (int r = 0; r < 4; ++r) st[r] = init_h[(size_t)(bb + r)*HID + jc];

  __shared__ f32x4  red1[3][4][64];   // az, ar, amx partials (12 KB)
  __shared__ f32x4  red2[4][64];      // amh partials (4 KB)
  __shared__ bf16x8 ewS[96][64];      // e-part weights: [hl*48 + kce*3 + gt][lane] (96 KB)

  // ---- preload e-part weights into LDS (once) ----
  for (int i = tid; i < 6144; i += 256) {
    int l = i & 63, row = i >> 6;             // row 0..95
    int hl = row / 48, rr2 = row % 48;        // rr2 = kce*3 + gt
    const bf16x8* src = (hl ? wl_all : wh_all) + ((size_t)jb*144 + rr2)*64 + l;
    ewS[row][l] = *src;
  }

  // ---- preload this wave's h-part W slice into registers (48 frags) ----
  const bf16x8* whB = wh_all + ((size_t)jb*144)*64 + lane;
  const bf16x8* wlB = wl_all + ((size_t)jb*144)*64 + lane;
  bf16x8 Wh[8][3], Wl[8][3];
  #pragma unroll
  for (int i = 0; i < 8; ++i) {
    int kc = 16 + w*8 + i;
    #pragma unroll
    for (int gt = 0; gt < 3; ++gt) {
      Wh[i][gt] = whB[(size_t)(kc*3 + gt)*64];
      Wl[i][gt] = wlB[(size_t)(kc*3 + gt)*64];
    }
  }
  __syncthreads();   // ewS ready

  // publish base (owner side), u32 index; r=0..3 at CONSECUTIVE addresses
  const int kc2w   = jc >> 5;
  const int l2base = ((jc & 31) >> 3) << 4;
  const int e7     = jc & 7;
  const size_t pub_base = (size_t)kc2w*512 + (size_t)e7*64 + (size_t)(l2base + rb);

  // gather bases (u32 granularity)
  const u32* hgrp0 = hp + (size_t)g*32768;            // buf 0
  const u32* hgrp1 = hgrp0 + 16384;                   // buf 1
  const u32* rgrp  = rp + (size_t)g*16384;
  const size_t woff = (size_t)w*4096 + (size_t)lane;

  // e-part A source: lane holds emb[t][g*16+c][kce*32+q*8 .. +7]
  const float* ebase = emb + (size_t)(g*16 + c)*INDIM + (q << 3);

  for (int t = 0; t < SEQ; ++t) {
    f32x4 az  = {0.f,0.f,0.f,0.f};
    f32x4 ar  = {0.f,0.f,0.f,0.f};
    f32x4 amx = {0.f,0.f,0.f,0.f};
    f32x4 amh = {0.f,0.f,0.f,0.f};

    // ---- e-part (x-projections, K-slice kce = w*4..w*4+3): overlaps h wait ----
    const float* et = ebase + (size_t)t*(BATCH*INDIM);
    #pragma unroll
    for (int qq = 0; qq < 4; ++qq) {
      int kce = w*4 + qq;
      const float* s = et + kce*32;
      float4 f0 = ((const float4*)s)[0];
      float4 f1 = ((const float4*)s)[1];
      float v[8] = {f0.x,f0.y,f0.z,f0.w,f1.x,f1.y,f1.z,f1.w};
      bf16x8 eh, el;
      #pragma unroll
      for (int j = 0; j < 8; ++j) {
        unsigned short a, b;
        splitf(v[j], a, b);
        eh[j] = (short)a; el[j] = (short)b;
      }
      int rowz = kce*3;
      bf16x8 wzh = ewS[rowz+0][lane], wzl = ewS[48+rowz+0][lane];
      bf16x8 wrh = ewS[rowz+1][lane], wrl = ewS[48+rowz+1][lane];
      bf16x8 wmh = ewS[rowz+2][lane], wml = ewS[48+rowz+2][lane];
      az  = MFMA16(eh, wzh, az);  az  = MFMA16(eh, wzl, az);  az  = MFMA16(el, wzh, az);
      ar  = MFMA16(eh, wrh, ar);  ar  = MFMA16(eh, wrl, ar);  ar  = MFMA16(el, wrh, ar);
      amx = MFMA16(eh, wmh, amx); amx = MFMA16(eh, wml, amx); amx = MFMA16(el, wmh, amx);
    }

    // ---- phase 1: wait producers' h(t), gather, z/r h-matmul over K-slice ----
    const int buf = t & 1;
    if (t > 0) waitf(fh_w, (unsigned)t);
    bf16x8 Ah[8], Al[8];
    loadfrags(Ah, Al, (buf ? hgrp1 : hgrp0) + woff);
    #pragma unroll
    for (int i = 0; i < 8; ++i) {
      az = MFMA16(Ah[i], Wh[i][0], az);
      az = MFMA16(Ah[i], Wl[i][0], az);
      az = MFMA16(Al[i], Wh[i][0], az);
      ar = MFMA16(Ah[i], Wh[i][1], ar);
      ar = MFMA16(Ah[i], Wl[i][1], ar);
      ar = MFMA16(Al[i], Wh[i][1], ar);
    }

    // ---- reduce az, ar (and amx, off the phase-2 critical path) ----
    red1[0][w][lane] = az;
    red1[1][w][lane] = ar;
    red1[2][w][lane] = amx;
    __syncthreads();                                   // S1
    f32x4 azF  = red1[0][0][lane] + red1[0][1][lane] + red1[0][2][lane] + red1[0][3][lane];
    f32x4 arF  = red1[1][0][lane] + red1[1][1][lane] + red1[1][2][lane] + red1[1][3][lane];
    f32x4 amxF = red1[2][0][lane] + red1[2][1][lane] + red1[2][2][lane] + red1[2][3][lane];

    // ---- pointwise 1 (wave 0 only): r, rh = r*h ; publish 2x8B, z deferred ----
    if (w == 0) {
      u32 wd[4];
      #pragma unroll
      for (int r = 0; r < 4; ++r) {
        float rr  = 1.f / (1.f + __expf(-(arF[r] + brj)));
        float rhv = rr * st[r];
        unsigned short sh, sl;
        splitf(rhv, sh, sl);
        wd[r] = ((u32)sh << 16) | (u32)sl;
      }
      ull* dst = (ull*)(rp + (size_t)g*16384 + pub_base);
      __hip_atomic_store(dst + 0, (ull)wd[0] | ((ull)wd[1] << 32),
                         __ATOMIC_RELAXED, __HIP_MEMORY_SCOPE_AGENT);
      __hip_atomic_store(dst + 1, (ull)wd[2] | ((ull)wd[3] << 32),
                         __ATOMIC_RELAXED, __HIP_MEMORY_SCOPE_AGENT);
    }
    if (tid == 0) {
      // manual release: drain wave-0's data-store acks, then relaxed flag.
      // (avoids the agent-release fence's conservative L2 writeback)
      asm volatile("s_waitcnt vmcnt(0)" ::: "memory");
      __hip_atomic_store(fr_g + (jb << 4), (unsigned)(t + 1),
                         __ATOMIC_RELAXED, __HIP_MEMORY_SCOPE_AGENT);
    }

    // ---- phase 2: wait producers' rh(t), gather, m h-matmul ----
    waitf(fr_w, (unsigned)(t + 1));
    bf16x8 Bh[8], Bl[8];
    loadfrags(Bh, Bl, rgrp + woff);
    // z-gate computed here: VALU overlaps the gather's load latency
    float z[4];
    #pragma unroll
    for (int r = 0; r < 4; ++r)
      z[r] = 1.f / (1.f + __expf(-(azF[r] + bzj)));
    #pragma unroll
    for (int i = 0; i < 8; ++i) {
      amh = MFMA16(Bh[i], Wh[i][2], amh);
      amh = MFMA16(Bh[i], Wl[i][2], amh);
      amh = MFMA16(Bl[i], Wh[i][2], amh);
    }

    // ---- reduce amh ----
    red2[w][lane] = amh;
    __syncthreads();                                   // S2
    f32x4 amhF = red2[0][lane] + red2[1][lane] + red2[2][lane] + red2[3][lane];

    // ---- pointwise 2: h_tilde, h_new ; publish h(t+1) (wave 0), manual release ----
    const int obuf = buf ^ 1;
    float hnv[4];
    u32 hd[4];
    #pragma unroll
    for (int r = 0; r < 4; ++r) {
      float pm = amxF[r] + bmj + amhF[r];
      float e2 = __expf(2.f*pm);
      float htl = 1.f - 2.f/(e2 + 1.f);
      float hn = st[r] + z[r]*(htl - st[r]);
      st[r] = hn; hnv[r] = hn;
      unsigned short sh, sl;
      splitf(hn, sh, sl);
      hd[r] = ((u32)sh << 16) | (u32)sl;
    }
    if (w == 0) {
      ull* hdst = (ull*)(hp + (size_t)g*32768 + (size_t)obuf*16384 + pub_base);
      __hip_atomic_store(hdst + 0, (ull)hd[0] | ((ull)hd[1] << 32),
                         __ATOMIC_RELAXED, __HIP_MEMORY_SCOPE_AGENT);
      __hip_atomic_store(hdst + 1, (ull)hd[2] | ((ull)hd[3] << 32),
                         __ATOMIC_RELAXED, __HIP_MEMORY_SCOPE_AGENT);
    }
    if (tid == 0) {
      asm volatile("s_waitcnt vmcnt(0)" ::: "memory");
      __hip_atomic_store(fh_g + (jb << 4), (unsigned)(t + 1),
                         __ATOMIC_RELAXED, __HIP_MEMORY_SCOPE_AGENT);
    }

    // ---- output on wave 1: keeps HBM store drains off wave 0's release path ----
    if (w == 1) {
      #pragma unroll
      for (int r = 0; r < 4; ++r)
        __builtin_nontemporal_store(hnv[r],
            out + (size_t)(bb + r)*(SEQ*HID) + (size_t)t*HID + jc);
    }
  }
}

extern "C" void kernel_launch(void* const* d_in, const int* in_sizes, int n_in,
                              void* d_out, int out_size, void* d_ws, size_t ws_size,
                              hipStream_t stream) {
  const float* emb = (const float*)d_in[0];
  const float* h0  = (const float*)d_in[1];
  const float* Wz  = (const float*)d_in[2];
  const float* bz  = (const float*)d_in[3];
  const float* Wr  = (const float*)d_in[4];
  const float* br  = (const float*)d_in[5];
  const float* Wm  = (const float*)d_in[6];
  const float* bm  = (const float*)d_in[7];
  float* out = (float*)d_out;

  if (ws_size < (size_t)WS_END) return;

  char* ws = (char*)d_ws;
  u32*    fhp = (u32*)(ws + WS_FH);
  u32*    frp = (u32*)(ws + WS_FR);
  u32*    hpp = (u32*)(ws + WS_HP);
  u32*    rpp = (u32*)(ws + WS_RP);
  bf16x8* wph = (bf16x8*)(ws + WS_WHI);
  bf16x8* wpl = (bf16x8*)(ws + WS_WLO);

  hipMemsetAsync(ws, 0, 32768, stream);                     // zero both flag arrays
  prep_w<<<2304, 256, 0, stream>>>(Wz, Wr, Wm, wph, wpl);
  prep_h<<<32,   256, 0, stream>>>(h0, hpp);
  gru_main<<<256, 256, 0, stream>>>(emb, bz, br, bm, h0, out,
                                    wph, wpl, hpp, rpp, fhp, frp);
}

// Round 7
// 4498.617 us; speedup vs baseline: 4.6091x; 1.0020x over previous
//
#include <hip/hip_runtime.h>
#include <cstdint>
#include <cstddef>

#define SEQ   512
#define BATCH 64
#define INDIM 512
#define HID   1024

typedef short bf16x8 __attribute__((ext_vector_type(8)));
typedef float f32x4  __attribute__((ext_vector_type(4)));
typedef unsigned long long ull;
typedef unsigned int u32;

#define MFMA16(A,B,C) __builtin_amdgcn_mfma_f32_16x16x32_bf16(A,B,C,0,0,0)

// ---- workspace layout (bytes) ----
// fh : [4 grp][64 jb][16] u32 flag lines                                16,384 B
// fr : same                                                             16,384 B
// hp : [4 grp][2 buf][32 kc][8 e][64 lane2] u32 (hi<<16|lo)            524,288 B
// rp : [4 grp][32 kc][8 e][64 lane2] u32                               262,144 B
// W_hi : [64 jb][48 kc][3 gate][64 lane][8] bf16                     9,437,184 B
// W_lo : same                                                        9,437,184 B
#define WS_FH  0
#define WS_FR  16384
#define WS_HP  32768
#define WS_RP  (WS_HP + 524288)
#define WS_WHI (WS_RP + 262144)
#define WS_WLO (WS_WHI + 9437184)
#define WS_END (WS_WLO + 9437184)   // 19,693,568 B

__device__ __forceinline__ unsigned short f2bf(float f) {
  unsigned u = __float_as_uint(f);
  unsigned r = (u + 0x7fffu + ((u >> 16) & 1u)) >> 16;  // RNE
  return (unsigned short)r;
}
__device__ __forceinline__ float bf2f(unsigned short h) {
  return __uint_as_float(((unsigned)h) << 16);
}
__device__ __forceinline__ void splitf(float x, unsigned short& hi, unsigned short& lo) {
  unsigned short h = f2bf(x);
  float r = x - bf2f(h);          // exact
  hi = h; lo = f2bf(r);           // combined rel err ~2^-18
}

// ---------------- prep: pack weights (B-fragment order, hi+lo) ----------------
__global__ void prep_w(const float* __restrict__ Wz, const float* __restrict__ Wr,
                       const float* __restrict__ Wm,
                       bf16x8* __restrict__ wh, bf16x8* __restrict__ wl) {
  int n    = blockIdx.x * 256 + threadIdx.x;     // 589,824 threads
  int lane = n & 63;
  int m    = n >> 6;
  int g    = m % 3;
  int m2   = m / 3;
  int kc   = m2 % 48;
  int jb   = m2 / 48;
  const float* W = (g == 0) ? Wz : (g == 1) ? Wr : Wm;
  int k0 = kc*32 + ((lane >> 4) << 3);
  int nn = jb*16 + (lane & 15);
  bf16x8 vh, vl;
  #pragma unroll
  for (int j = 0; j < 8; ++j) {
    unsigned short a, b;
    splitf(W[(size_t)(k0 + j)*HID + nn], a, b);
    vh[j] = (short)a; vl[j] = (short)b;
  }
  wh[n] = vh; wl[n] = vl;
}

// ---------------- prep: pack init_h (packed u32) into buf 0 ----------------
// slot(b,col) = grp(b>>4) buf0 : [kc=col>>5][e=col&7][lane2=(b&15)+((col>>3)&3)*16]
__global__ void prep_h(const float* __restrict__ h0, u32* __restrict__ hp) {
  int n = blockIdx.x * 256 + threadIdx.x;        // 8192 threads
  int b = n >> 7;
  int j = (n & 127) << 3;
  const float* s = h0 + (size_t)b*HID + j;
  float4 f0 = ((const float4*)s)[0];
  float4 f1 = ((const float4*)s)[1];
  float v[8] = {f0.x,f0.y,f0.z,f0.w,f1.x,f1.y,f1.z,f1.w};
  int g     = b >> 4;
  int kc2   = j >> 5;
  int lane2 = (b & 15) + (((j >> 3) & 3) << 4);
  size_t base = (size_t)g*32768 + (size_t)kc2*512 + (size_t)lane2;  // buf 0
  #pragma unroll
  for (int q = 0; q < 8; ++q) {
    unsigned short a, c;
    splitf(v[q], a, c);
    hp[base + (size_t)q*64] = ((u32)a << 16) | (u32)c;
  }
}

// per-wave wait: lanes 0..7 poll the wave's 8 producer flags, exit on ballot
__device__ __forceinline__ void waitf(const u32* f, unsigned tgt, bool poller) {
  for (;;) {
    unsigned v = tgt;
    if (poller)
      v = __hip_atomic_load(f, __ATOMIC_RELAXED, __HIP_MEMORY_SCOPE_AGENT);
    if (__ballot(v >= tgt) == ~0ull) return;
    __builtin_amdgcn_s_sleep(1);
  }
}

// load 4 A-fragments (hi+lo); frag i at base + i*512, element e at + e*64,
// lane innermost => every load instruction is 256 B contiguous across the wave.
__device__ __forceinline__ void loadfrags4(bf16x8* Fh, bf16x8* Fl,
                                           const u32* __restrict__ base32) {
  #pragma unroll
  for (int i = 0; i < 4; ++i) {
    u32 wv[8];
    #pragma unroll
    for (int e = 0; e < 8; ++e)
      wv[e] = __hip_atomic_load(base32 + (size_t)i*512 + (size_t)e*64,
                                __ATOMIC_RELAXED, __HIP_MEMORY_SCOPE_AGENT);
    bf16x8 h8, l8;
    #pragma unroll
    for (int e = 0; e < 8; ++e) {
      h8[e] = (short)(wv[e] >> 16);
      l8[e] = (short)(wv[e] & 0xffffu);
    }
    Fh[i] = h8; Fl[i] = l8;
  }
}

#define SUM8(A, l) (((A[0][l]+A[1][l])+(A[2][l]+A[3][l])) + \
                    ((A[4][l]+A[5][l])+(A[6][l]+A[7][l])))

// ---------------- main persistent GRU kernel ----------------
// 256 blocks x 512 threads (8 waves). blockIdx = g*64 + jb.
// Block (g,jb): batch rows [g*16,+16), HID cols [jb*16,+16), full K.
// 8 waves K-split (4 kc h-part, 2 kce e-part each); partials reduced via LDS.
// Exchange: packed-u32, per-producer flag; manual release (vmcnt drain + relaxed).
// amx/z/azF and emb(t+1) prefetch fill the phase-2 (rh) wait window.
__global__ __launch_bounds__(512, 1)
void gru_main(const float* __restrict__ emb,
              const float* __restrict__ bz, const float* __restrict__ br,
              const float* __restrict__ bm, const float* __restrict__ init_h,
              float* __restrict__ out,
              const bf16x8* __restrict__ wh_all, const bf16x8* __restrict__ wl_all,
              u32* __restrict__ hp, u32* __restrict__ rp,
              u32* __restrict__ fh, u32* __restrict__ fr)
{
  const int tid  = threadIdx.x;
  const int w    = tid >> 6;              // 0..7
  const int lane = tid & 63;
  const int jb   = blockIdx.x & 63;
  const int g    = blockIdx.x >> 6;
  const int c    = lane & 15;
  const int q    = lane >> 4;
  const int jc   = jb*16 + c;             // C/D col
  const int rb   = q << 2;                // C/D row base within 16-row tile
  const int bb   = g*16 + rb;             // global batch row base

  u32* fh_g = fh + g*1024;
  u32* fr_g = fr + g*1024;
  const u32* fh_w = fh_g + ((w*8 + (lane & 7)) << 4);   // this wave's 8 producers
  const u32* fr_w = fr_g + ((w*8 + (lane & 7)) << 4);
  const bool poller = (lane < 8);

  const float bzj = bz[jc], brj = br[jc], bmj = bm[jc];
  float st[4];
  #pragma unroll
  for (int r = 0; r < 4; ++r) st[r] = init_h[(size_t)(bb + r)*HID + jc];

  __shared__ f32x4 redA[2][8][64];   // az, ar partials   (S1)
  __shared__ f32x4 redM[2][8][64];   // amx, amh partials (S2)

  // ---- preload this wave's weight slices into registers ----
  const bf16x8* whB = wh_all + ((size_t)jb*144)*64 + lane;
  const bf16x8* wlB = wl_all + ((size_t)jb*144)*64 + lane;
  bf16x8 Wh[4][3], Wl[4][3];          // h-part: kc = 16 + w*4 + i
  #pragma unroll
  for (int i = 0; i < 4; ++i) {
    int kc = 16 + w*4 + i;
    #pragma unroll
    for (int gt = 0; gt < 3; ++gt) {
      Wh[i][gt] = whB[(size_t)(kc*3 + gt)*64];
      Wl[i][gt] = wlB[(size_t)(kc*3 + gt)*64];
    }
  }
  bf16x8 Eh[2][3], El[2][3];          // e-part: kce = w*2 + j
  #pragma unroll
  for (int j = 0; j < 2; ++j) {
    int kce = w*2 + j;
    #pragma unroll
    for (int gt = 0; gt < 3; ++gt) {
      Eh[j][gt] = whB[(size_t)(kce*3 + gt)*64];
      El[j][gt] = wlB[(size_t)(kce*3 + gt)*64];
    }
  }

  // publish base (owner side), u32 index; r=0..3 at CONSECUTIVE addresses
  const int kc2w   = jc >> 5;
  const int l2base = ((jc & 31) >> 3) << 4;
  const int e7     = jc & 7;
  const size_t pub_base = (size_t)kc2w*512 + (size_t)e7*64 + (size_t)(l2base + rb);

  // gather bases (u32 granularity): frag i at + (w*4+i)*512 + e*64 + lane
  const u32* hgrp0 = hp + (size_t)g*32768;            // buf 0
  const u32* hgrp1 = hgrp0 + 16384;                   // buf 1
  const u32* rgrp  = rp + (size_t)g*16384;
  const size_t woff = (size_t)w*2048 + (size_t)lane;

  // e-part A source: lane holds emb[t][g*16+c][kce*32+q*8 .. +7]
  const float* ebase = emb + (size_t)(g*16 + c)*INDIM + (q << 3);

  // ---- software-pipelined emb: load t=0 now, prefetch t+1 each step ----
  float4 pf[2][2];
  #pragma unroll
  for (int j = 0; j < 2; ++j) {
    const float* s = ebase + (size_t)(w*2 + j)*32;
    pf[j][0] = ((const float4*)s)[0];
    pf[j][1] = ((const float4*)s)[1];
  }

  for (int t = 0; t < SEQ; ++t) {
    // ---- unpack prefetched emb, keep eh/el live for amx later ----
    bf16x8 eh[2], el[2];
    #pragma unroll
    for (int j = 0; j < 2; ++j) {
      float v[8] = {pf[j][0].x, pf[j][0].y, pf[j][0].z, pf[j][0].w,
                    pf[j][1].x, pf[j][1].y, pf[j][1].z, pf[j][1].w};
      bf16x8 a8, b8;
      #pragma unroll
      for (int k = 0; k < 8; ++k) {
        unsigned short a, b;
        splitf(v[k], a, b);
        a8[k] = (short)a; b8[k] = (short)b;
      }
      eh[j] = a8; el[j] = b8;
    }

    f32x4 az = {0.f,0.f,0.f,0.f};
    f32x4 ar = {0.f,0.f,0.f,0.f};

    // ---- e-part z/r only (amx deferred to the phase-2 window) ----
    #pragma unroll
    for (int j = 0; j < 2; ++j) {
      az = MFMA16(eh[j], Eh[j][0], az);
      az = MFMA16(eh[j], El[j][0], az);
      az = MFMA16(el[j], Eh[j][0], az);
      ar = MFMA16(eh[j], Eh[j][1], ar);
      ar = MFMA16(eh[j], El[j][1], ar);
      ar = MFMA16(el[j], Eh[j][1], ar);
    }

    // ---- phase 1: wait producers' h(t), gather, z/r h-matmul ----
    const int buf = t & 1;
    if (t > 0) waitf(fh_w, (unsigned)t, poller);
    {
      bf16x8 Ah[4], Al[4];
      loadfrags4(Ah, Al, (buf ? hgrp1 : hgrp0) + woff);
      #pragma unroll
      for (int i = 0; i < 4; ++i) {
        az = MFMA16(Ah[i], Wh[i][0], az);
        az = MFMA16(Ah[i], Wl[i][0], az);
        az = MFMA16(Al[i], Wh[i][0], az);
        ar = MFMA16(Ah[i], Wh[i][1], ar);
        ar = MFMA16(Ah[i], Wl[i][1], ar);
        ar = MFMA16(Al[i], Wh[i][1], ar);
      }
    }

    redA[0][w][lane] = az;
    redA[1][w][lane] = ar;
    __syncthreads();                                   // S1
    f32x4 arF = SUM8(redA[1], lane);

    // ---- pointwise 1 (wave 0): r, rh = r*h ; publish 2x8B, manual release ----
    if (w == 0) {
      u32 wd[4];
      #pragma unroll
      for (int r = 0; r < 4; ++r) {
        float rr  = 1.f / (1.f + __expf(-(arF[r] + brj)));
        float rhv = rr * st[r];
        unsigned short sh, sl;
        splitf(rhv, sh, sl);
        wd[r] = ((u32)sh << 16) | (u32)sl;
      }
      ull* dst = (ull*)(rp + (size_t)g*16384 + pub_base);
      __hip_atomic_store(dst + 0, (ull)wd[0] | ((ull)wd[1] << 32),
                         __ATOMIC_RELAXED, __HIP_MEMORY_SCOPE_AGENT);
      __hip_atomic_store(dst + 1, (ull)wd[2] | ((ull)wd[3] << 32),
                         __ATOMIC_RELAXED, __HIP_MEMORY_SCOPE_AGENT);
    }
    if (tid == 0) {
      asm volatile("s_waitcnt vmcnt(0)" ::: "memory");
      __hip_atomic_store(fr_g + (jb << 4), (unsigned)(t + 1),
                         __ATOMIC_RELAXED, __HIP_MEMORY_SCOPE_AGENT);
    }

    // ---- phase-2 window: amx e-MFMAs, azF, z, emb(t+1) prefetch (hides rh hop) ----
    f32x4 amx = {0.f,0.f,0.f,0.f};
    #pragma unroll
    for (int j = 0; j < 2; ++j) {
      amx = MFMA16(eh[j], Eh[j][2], amx);
      amx = MFMA16(eh[j], El[j][2], amx);
      amx = MFMA16(el[j], Eh[j][2], amx);
    }
    f32x4 azF = SUM8(redA[0], lane);
    float z[4];
    #pragma unroll
    for (int r = 0; r < 4; ++r)
      z[r] = 1.f / (1.f + __expf(-(azF[r] + bzj)));
    {
      int tn = (t + 1 < SEQ) ? (t + 1) : t;
      const float* et = ebase + (size_t)tn*(BATCH*INDIM);
      #pragma unroll
      for (int j = 0; j < 2; ++j) {
        const float* s = et + (size_t)(w*2 + j)*32;
        pf[j][0] = ((const float4*)s)[0];
        pf[j][1] = ((const float4*)s)[1];
      }
    }

    // ---- phase 2: wait producers' rh(t), gather, m h-matmul ----
    waitf(fr_w, (unsigned)(t + 1), poller);
    f32x4 amh = {0.f,0.f,0.f,0.f};
    {
      bf16x8 Bh[4], Bl[4];
      loadfrags4(Bh, Bl, rgrp + woff);
      #pragma unroll
      for (int i = 0; i < 4; ++i) {
        amh = MFMA16(Bh[i], Wh[i][2], amh);
        amh = MFMA16(Bh[i], Wl[i][2], amh);
        amh = MFMA16(Bl[i], Wh[i][2], amh);
      }
    }

    redM[0][w][lane] = amx;
    redM[1][w][lane] = amh;
    __syncthreads();                                   // S2
    f32x4 amxF = SUM8(redM[0], lane);
    f32x4 amhF = SUM8(redM[1], lane);

    // ---- pointwise 2: h_tilde, h_new ; publish h(t+1) (wave 0), manual release ----
    const int obuf = buf ^ 1;
    float hnv[4];
    u32 hd[4];
    #pragma unroll
    for (int r = 0; r < 4; ++r) {
      float pm = amxF[r] + bmj + amhF[r];
      float e2 = __expf(2.f*pm);
      float htl = 1.f - 2.f/(e2 + 1.f);
      float hn = st[r] + z[r]*(htl - st[r]);
      st[r] = hn; hnv[r] = hn;
      unsigned short sh, sl;
      splitf(hn, sh, sl);
      hd[r] = ((u32)sh << 16) | (u32)sl;
    }
    if (w == 0) {
      ull* hdst = (ull*)(hp + (size_t)g*32768 + (size_t)obuf*16384 + pub_base);
      __hip_atomic_store(hdst + 0, (ull)hd[0] | ((ull)hd[1] << 32),
                         __ATOMIC_RELAXED, __HIP_MEMORY_SCOPE_AGENT);
      __hip_atomic_store(hdst + 1, (ull)hd[2] | ((ull)hd[3] << 32),
                         __ATOMIC_RELAXED, __HIP_MEMORY_SCOPE_AGENT);
    }
    if (tid == 0) {
      asm volatile("s_waitcnt vmcnt(0)" ::: "memory");
      __hip_atomic_store(fh_g + (jb << 4), (unsigned)(t + 1),
                         __ATOMIC_RELAXED, __HIP_MEMORY_SCOPE_AGENT);
    }

    // ---- output on wave 1: keeps HBM store drains off wave 0's release path ----
    if (w == 1) {
      #pragma unroll
      for (int r = 0; r < 4; ++r)
        __builtin_nontemporal_store(hnv[r],
            out + (size_t)(bb + r)*(SEQ*HID) + (size_t)t*HID + jc);
    }
  }
}

extern "C" void kernel_launch(void* const* d_in, const int* in_sizes, int n_in,
                              void* d_out, int out_size, void* d_ws, size_t ws_size,
                              hipStream_t stream) {
  const float* emb = (const float*)d_in[0];
  const float* h0  = (const float*)d_in[1];
  const float* Wz  = (const float*)d_in[2];
  const float* bz  = (const float*)d_in[3];
  const float* Wr  = (const float*)d_in[4];
  const float* br  = (const float*)d_in[5];
  const float* Wm  = (const float*)d_in[6];
  const float* bm  = (const float*)d_in[7];
  float* out = (float*)d_out;

  if (ws_size < (size_t)WS_END) return;

  char* ws = (char*)d_ws;
  u32*    fhp = (u32*)(ws + WS_FH);
  u32*    frp = (u32*)(ws + WS_FR);
  u32*    hpp = (u32*)(ws + WS_HP);
  u32*    rpp = (u32*)(ws + WS_RP);
  bf16x8* wph = (bf16x8*)(ws + WS_WHI);
  bf16x8* wpl = (bf16x8*)(ws + WS_WLO);

  hipMemsetAsync(ws, 0, 32768, stream);                     // zero both flag arrays
  prep_w<<<2304, 256, 0, stream>>>(Wz, Wr, Wm, wph, wpl);
  prep_h<<<32,   256, 0, stream>>>(h0, hpp);
  gru_main<<<256, 512, 0, stream>>>(emb, bz, br, bm, h0, out,
                                    wph, wpl, hpp, rpp, fhp, frp);
}